// Round 2
// baseline (1448.789 us; speedup 1.0000x reference)
//
#include <hip/hip_runtime.h>
#include <cstdint>
#include <cstddef>

typedef float        f32x4  __attribute__((ext_vector_type(4)));
typedef __bf16       bf16x8 __attribute__((ext_vector_type(8)));
typedef unsigned int u32x4  __attribute__((ext_vector_type(4)));
typedef unsigned int u32x2  __attribute__((ext_vector_type(2)));

// ---------------- problem dims ----------------
static constexpr int HID   = 1536;
static constexpr int NHEAD = 12;
static constexpr int HD    = 128;
static constexpr int NQKV  = 10752;   // 3*HID + 4*HID
static constexpr int CATK  = 7680;    // HID + 4*HID
static constexpr int LX    = 4352;    // text 256 + 4096 image
static constexpr int LC2   = 4116;    // 20 concepts + 4096 image
static constexpr int NCON  = 20;

// q pre-scale: 1/sqrt(128) * log2(e)  (softmax computed in exp2 domain)
static constexpr float QSCL = 0.08838834764831845f * 1.4426950408889634f;

// ---------------- workspace layout (bytes) ----------------
static constexpr size_t OFF_MVEC = 0;                          // 4608 f32
static constexpr size_t OFF_W1B  = 18432;                      // 10752x1536 bf16
static constexpr size_t OFF_W2B  = OFF_W1B  + 33030144ull;     // 1536x7680 bf16
static constexpr size_t OFF_XM1  = OFF_W2B  + 23592960ull;     // 4352x1536 bf16 (later aliased by qh1)
static constexpr size_t OFF_QH1  = OFF_XM1;                    // [12][4352][128] bf16
static constexpr size_t OFF_QKV1 = OFF_XM1  + 13369344ull;     // 4352x3072 bf16 (q,k raw)
static constexpr size_t OFF_KH1  = OFF_QKV1 + 26738688ull;     // [12][4352][128]
static constexpr size_t OFF_VH1  = OFF_KH1  + 13369344ull;     // [12][128][4352] (transposed)
static constexpr size_t OFF_CAT1 = OFF_VH1  + 13369344ull;     // 4352x7680 bf16
// block-2 scratch aliased inside cat1 (cat1 dead after GEMM2 of block 1):
static constexpr size_t OFF_XM2  = OFF_CAT1;                   // 64x1536 bf16
static constexpr size_t OFF_QKV2 = OFF_XM2  + 196608ull;       // 32x3072 bf16
static constexpr size_t OFF_VH2S = OFF_QKV2 + 196608ull;       // [12][128][32]
static constexpr size_t OFF_QH2  = OFF_VH2S + 98304ull;        // [12][64][128]
static constexpr size_t OFF_KH2  = OFF_QH2  + 196608ull;       // [12][4116][128]
static constexpr size_t OFF_CAT2 = OFF_KH2  + 12644352ull;     // 32x7680 bf16
// total required: OFF_CAT1 + 66846720 = 190,334,976 bytes

// async global->LDS, 16B per lane. LDS dest must be wave-uniform base; HW
// writes base + lane*16 (m104). Global src is per-lane.
__device__ __forceinline__ void gload_lds16(const void* g, void* l)
{
  __builtin_amdgcn_global_load_lds(
      (const __attribute__((address_space(1))) unsigned int*)g,
      (__attribute__((address_space(3))) unsigned int*)l, 16, 0, 0);
}

// raw barrier: drains this wave's LDS ops (cross-wave overwrite safety) but
// does NOT drain vmcnt — the counted-vmcnt pipeline survives the barrier.
__device__ __forceinline__ void wg_barrier()
{
  asm volatile("s_waitcnt lgkmcnt(0)\n\ts_barrier" ::: "memory");
}

// ---------------- small kernels ----------------

__global__ __launch_bounds__(256) void f2b_kernel(const float* __restrict__ in,
                                                  __bf16* __restrict__ out, int n4)
{
  int i = blockIdx.x * 256 + threadIdx.x;
  if (i >= n4) return;
  f32x4 v = *((const f32x4*)in + i);
  union { __bf16 h[4]; u32x2 u; } cv;
  cv.h[0] = (__bf16)v[0]; cv.h[1] = (__bf16)v[1];
  cv.h[2] = (__bf16)v[2]; cv.h[3] = (__bf16)v[3];
  *((u32x2*)out + i) = cv.u;
}

// m = silu(vec) @ mod_w.T + mod_b   (one wave per output)
__global__ __launch_bounds__(256) void mod_kernel(const float* __restrict__ vec,
                                                  const float* __restrict__ mod_w,
                                                  const float* __restrict__ mod_b,
                                                  float* __restrict__ m)
{
  int o = blockIdx.x * 4 + (threadIdx.x >> 6);
  int lane = threadIdx.x & 63;
  float s = 0.0f;
  for (int k = lane; k < HID; k += 64) {
    float v = vec[k];
    float sv = v / (1.0f + expf(-v));
    s += sv * mod_w[(size_t)o * HID + k];
  }
  #pragma unroll
  for (int msk = 32; msk; msk >>= 1) s += __shfl_xor(s, msk);
  if (lane == 0) m[o] = s + mod_b[o];
}

__device__ __forceinline__ float block_sum256(float v, float* red)
{
  #pragma unroll
  for (int msk = 32; msk; msk >>= 1) v += __shfl_xor(v, msk);
  int w = threadIdx.x >> 6;
  if ((threadIdx.x & 63) == 0) red[w] = v;
  __syncthreads();
  float s = red[0] + red[1] + red[2] + red[3];
  __syncthreads();
  return s;
}

// xm = (1+scale)*layernorm(x) + shift, bf16 out. one block per row.
__global__ __launch_bounds__(256) void ln_mod_kernel(const float* __restrict__ x,
                                                     const float* __restrict__ mvec,
                                                     __bf16* __restrict__ out)
{
  __shared__ float red[4];
  size_t row = blockIdx.x;
  const float* xr = x + row * HID;
  float v[6]; float s = 0.0f;
  #pragma unroll
  for (int i = 0; i < 6; i++) { v[i] = xr[threadIdx.x + i * 256]; s += v[i]; }
  float mu = block_sum256(s, red) * (1.0f / HID);
  float s2 = 0.0f;
  #pragma unroll
  for (int i = 0; i < 6; i++) { float d = v[i] - mu; s2 += d * d; }
  float var = block_sum256(s2, red) * (1.0f / HID);
  float rinv = rsqrtf(var + 1e-6f);
  #pragma unroll
  for (int i = 0; i < 6; i++) {
    int h = threadIdx.x + i * 256;
    float xm = (v[i] - mu) * rinv;
    xm = (1.0f + mvec[HID + h]) * xm + mvec[h];
    out[row * HID + h] = (__bf16)xm;
  }
}

// ---------------- 256x256 8-phase GEMM (B^T layout): C[m,n]=sum_k A[m,k]B[n,k]
// 512 threads = 8 waves (2M x 4N), per-wave output 128x64, BK=64.
// LDS 128 KiB: As/Bs[2][256][64] double-buffered.
// T2 swizzle: LDS[row][col] holds global col (col ^ ((row&4)?16:0)) —
//   st_16x32 (byte ^= ((byte>>9)&1)<<5) — kills the 16-way b128 conflict.
//   Applied by pre-swizzling the global source (gload_lds dest is linear).
// T3/T4: per K-tile 4 phases x {ds_read; stage; barrier; MFMA16; barrier};
//   B(t+2) staged in phase 2 (B region dead after phase 1), A(t+2) in
//   phase 3 (A dead after phase 2); vmcnt(8) once per tile (8 stage loads
//   per tile in flight), vmcnt(0) only at the epilogue drain.
// T5: setprio(1) around each 16-MFMA cluster.
template<int MODE>
__global__ __launch_bounds__(512, 2) void gemm256(const __bf16* __restrict__ A,
                                                  const __bf16* __restrict__ B,
                                                  int M, int K,
                                                  const float* __restrict__ bias,
                                                  __bf16* __restrict__ qkv_out,
                                                  __bf16* __restrict__ cat_out,
                                                  __bf16* __restrict__ vh_out, int vkeys,
                                                  const float* __restrict__ res,
                                                  const float* __restrict__ gate,
                                                  float* __restrict__ out)
{
  const int tid = threadIdx.x;
  const int lane = tid & 63, wave = tid >> 6;
  const int quad = lane >> 4, l16 = lane & 15;
  const int wmh = wave >> 2;            // M half (0/1) -> rows wmh*128..+127
  const int wnq = wave & 3;             // N quarter    -> cols wnq*64..+63
  const int m0 = blockIdx.y * 256, n0 = blockIdx.x * 256;
  const int swz = (l16 & 4) ? 16 : 0;   // read-side XOR (row&4 == l16&4)

  __shared__ __bf16 As[2][256][64];
  __shared__ __bf16 Bs[2][256][64];

  const f32x4 fzero = {0.0f, 0.0f, 0.0f, 0.0f};
  f32x4 acc[8][4];
  #pragma unroll
  for (int i = 0; i < 8; i++)
    #pragma unroll
    for (int j = 0; j < 4; j++) acc[i][j] = fzero;

  // staging: wave w owns A rows [w*32,+32) and B rows [w*32,+32); 4 issues
  // each (8 rows x 128B per issue). lane -> (row=l>>3, colbyte=(l&7)*16);
  // source col pre-swizzled so LDS ends up st_16x32-swizzled.
  const int srow = lane >> 3;
  const int scol = ((lane & 7) * 8) ^ ((lane & 32) ? 16 : 0);
  const __bf16* Ag = A + (size_t)(m0 + wave * 32 + srow) * K + scol;
  const __bf16* Bg = B + (size_t)(n0 + wave * 32 + srow) * K + scol;

  auto stageA = [&](int buf, int k) {
    #pragma unroll
    for (int j = 0; j < 4; j++)
      gload_lds16(Ag + (size_t)(j * 8) * K + k, &As[buf][wave * 32 + j * 8][0]);
  };
  auto stageB = [&](int buf, int k) {
    #pragma unroll
    for (int j = 0; j < 4; j++)
      gload_lds16(Bg + (size_t)(j * 8) * K + k, &Bs[buf][wave * 32 + j * 8][0]);
  };

  const int NT = K >> 6;
  // prologue: tiles 0 and 1. S(0)=first 8 issues, S(1)=next 8.
  stageB(0, 0);  stageA(0, 0);
  stageB(1, 64); stageA(1, 64);
  asm volatile("s_waitcnt vmcnt(8)" ::: "memory");   // S(0) landed
  wg_barrier();

  for (int t = 0; t < NT; ++t) {
    const int b = t & 1;
    const int kn = (t + 2) << 6;
    bf16x8 aM[4][2], bN0[2][2], bN1[2][2];

    // ---- phase 0: quadrant (M0,N0); 12 ds_reads ----
    #pragma unroll
    for (int f = 0; f < 4; f++)
      #pragma unroll
      for (int kk = 0; kk < 2; kk++)
        aM[f][kk] = *(const bf16x8*)&As[b][wmh * 128 + f * 16 + l16][(kk * 32 + quad * 8) ^ swz];
    #pragma unroll
    for (int g = 0; g < 2; g++)
      #pragma unroll
      for (int kk = 0; kk < 2; kk++)
        bN0[g][kk] = *(const bf16x8*)&Bs[b][wnq * 64 + g * 16 + l16][(kk * 32 + quad * 8) ^ swz];
    wg_barrier();
    __builtin_amdgcn_s_setprio(1);
    #pragma unroll
    for (int f = 0; f < 4; f++)
      #pragma unroll
      for (int g = 0; g < 2; g++)
        #pragma unroll
        for (int kk = 0; kk < 2; kk++)
          acc[f][g] = __builtin_amdgcn_mfma_f32_16x16x32_bf16(aM[f][kk], bN0[g][kk], acc[f][g], 0, 0, 0);
    __builtin_amdgcn_s_setprio(0);
    wg_barrier();

    // ---- phase 1: (M0,N1); 4 ds_reads ----
    #pragma unroll
    for (int g = 0; g < 2; g++)
      #pragma unroll
      for (int kk = 0; kk < 2; kk++)
        bN1[g][kk] = *(const bf16x8*)&Bs[b][wnq * 64 + 32 + g * 16 + l16][(kk * 32 + quad * 8) ^ swz];
    wg_barrier();
    __builtin_amdgcn_s_setprio(1);
    #pragma unroll
    for (int f = 0; f < 4; f++)
      #pragma unroll
      for (int g = 0; g < 2; g++)
        #pragma unroll
        for (int kk = 0; kk < 2; kk++)
          acc[f][2 + g] = __builtin_amdgcn_mfma_f32_16x16x32_bf16(aM[f][kk], bN1[g][kk], acc[f][2 + g], 0, 0, 0);
    __builtin_amdgcn_s_setprio(0);
    wg_barrier();

    // ---- phase 2: (M1,N1); 8 ds_reads; stage B(t+2) (B region dead) ----
    #pragma unroll
    for (int f = 0; f < 4; f++)
      #pragma unroll
      for (int kk = 0; kk < 2; kk++)
        aM[f][kk] = *(const bf16x8*)&As[b][wmh * 128 + 64 + f * 16 + l16][(kk * 32 + quad * 8) ^ swz];
    if (t + 2 < NT) stageB(b, kn);
    wg_barrier();
    __builtin_amdgcn_s_setprio(1);
    #pragma unroll
    for (int f = 0; f < 4; f++)
      #pragma unroll
      for (int g = 0; g < 2; g++)
        #pragma unroll
        for (int kk = 0; kk < 2; kk++)
          acc[4 + f][2 + g] = __builtin_amdgcn_mfma_f32_16x16x32_bf16(aM[f][kk], bN1[g][kk], acc[4 + f][2 + g], 0, 0, 0);
    __builtin_amdgcn_s_setprio(0);
    wg_barrier();

    // ---- phase 3: (M1,N0); stage A(t+2) (A region dead); tile-boundary vmcnt ----
    if (t + 2 < NT) stageA(b, kn);
    wg_barrier();
    __builtin_amdgcn_s_setprio(1);
    #pragma unroll
    for (int f = 0; f < 4; f++)
      #pragma unroll
      for (int g = 0; g < 2; g++)
        #pragma unroll
        for (int kk = 0; kk < 2; kk++)
          acc[4 + f][g] = __builtin_amdgcn_mfma_f32_16x16x32_bf16(aM[f][kk], bN0[g][kk], acc[4 + f][g], 0, 0, 0);
    __builtin_amdgcn_s_setprio(0);
    if (t + 1 < NT) {
      if (t + 2 < NT) asm volatile("s_waitcnt vmcnt(8)" ::: "memory");  // S(t+1) landed, S(t+2) in flight
      else            asm volatile("s_waitcnt vmcnt(0)" ::: "memory");  // final drain
    }
    wg_barrier();
  }

  // ---- epilogue ----
  #pragma unroll
  for (int mf = 0; mf < 8; mf++) {
    #pragma unroll
    for (int r = 0; r < 4; r++) {
      int gm = m0 + wmh * 128 + mf * 16 + quad * 4 + r;
      if (gm >= M) continue;
      #pragma unroll
      for (int nf = 0; nf < 4; nf++) {
        int gn = n0 + wnq * 64 + nf * 16 + l16;
        float v = acc[mf][nf][r] + bias[gn];
        if constexpr (MODE == 0) {
          if (gn < 3072) {                 // q,k raw
            qkv_out[(size_t)gm * 3072 + gn] = (__bf16)v;
          } else if (gn < 4608) {          // v -> transposed [head*128+d][key]
            vh_out[(size_t)(gn - 3072) * vkeys + gm] = (__bf16)v;
          } else {                         // mlp -> gelu -> cat cols [1536,7680)
            float g = 0.5f * v * (1.0f + tanhf(0.7978845608028654f * (v + 0.044715f * v * v * v)));
            cat_out[(size_t)gm * CATK + (gn - 3072)] = (__bf16)g;
          }
        } else {
          out[(size_t)gm * HID + gn] = res[(size_t)gm * HID + gn] + gate[gn] * v;
        }
      }
    }
  }
}

// ---------------- legacy 128x128 GEMM (block-2 small dispatches, M=20) ----
template<int MODE>
__global__ __launch_bounds__(256) void gemm_bt(const __bf16* __restrict__ A,
                                               const __bf16* __restrict__ B,
                                               int M, int K,
                                               const float* __restrict__ bias,
                                               __bf16* __restrict__ qkv_out,
                                               __bf16* __restrict__ cat_out,
                                               __bf16* __restrict__ vh_out, int vkeys,
                                               const float* __restrict__ res,
                                               const float* __restrict__ gate,
                                               float* __restrict__ out)
{
  const int tid = threadIdx.x;
  const int lane = tid & 63, wave = tid >> 6;
  const int quad = lane >> 4, l16 = lane & 15;
  const int m0 = blockIdx.y * 128, n0 = blockIdx.x * 128;
  const int wm = (wave & 1) * 64, wn = (wave >> 1) * 64;

  __shared__ __bf16 As[128][64];
  __shared__ __bf16 Bs[128][64];

  const f32x4 fzero = {0.0f, 0.0f, 0.0f, 0.0f};
  f32x4 acc[4][4];
  #pragma unroll
  for (int i = 0; i < 4; i++)
    #pragma unroll
    for (int j = 0; j < 4; j++) acc[i][j] = fzero;

  const int srow = lane >> 3;
  const int scol = (lane & 7) * 8;
  const int rbase = wave * 32 + srow;
  const __bf16* Ab = A + (size_t)(m0 + rbase) * K + scol;
  const __bf16* Bb = B + (size_t)(n0 + rbase) * K + scol;

  for (int k0 = 0; k0 < K; k0 += 64) {
    __syncthreads();
    #pragma unroll
    for (int j = 0; j < 4; j++) {
      gload_lds16(Ab + (size_t)(j * 8) * K + k0, &As[wave * 32 + j * 8][0]);
      gload_lds16(Bb + (size_t)(j * 8) * K + k0, &Bs[wave * 32 + j * 8][0]);
    }
    __syncthreads();
    #pragma unroll
    for (int kk = 0; kk < 64; kk += 32) {
      bf16x8 af[4], bfr[4];
      #pragma unroll
      for (int i = 0; i < 4; i++) af[i]  = *(const bf16x8*)&As[wm + i * 16 + l16][kk + quad * 8];
      #pragma unroll
      for (int j = 0; j < 4; j++) bfr[j] = *(const bf16x8*)&Bs[wn + j * 16 + l16][kk + quad * 8];
      #pragma unroll
      for (int i = 0; i < 4; i++)
        #pragma unroll
        for (int j = 0; j < 4; j++)
          acc[i][j] = __builtin_amdgcn_mfma_f32_16x16x32_bf16(af[i], bfr[j], acc[i][j], 0, 0, 0);
    }
  }

  #pragma unroll
  for (int i = 0; i < 4; i++) {
    #pragma unroll
    for (int r = 0; r < 4; r++) {
      int gm = m0 + wm + i * 16 + quad * 4 + r;
      if (gm >= M) continue;
      #pragma unroll
      for (int j = 0; j < 4; j++) {
        int gn = n0 + wn + j * 16 + l16;
        float v = acc[i][j][r] + bias[gn];
        if constexpr (MODE == 0) {
          if (gn < 3072) {
            qkv_out[(size_t)gm * 3072 + gn] = (__bf16)v;
          } else if (gn < 4608) {
            vh_out[(size_t)(gn - 3072) * vkeys + gm] = (__bf16)v;
          } else {
            float g = 0.5f * v * (1.0f + tanhf(0.7978845608028654f * (v + 0.044715f * v * v * v)));
            cat_out[(size_t)gm * CATK + (gn - 3072)] = (__bf16)g;
          }
        } else {
          out[(size_t)gm * HID + gn] = res[(size_t)gm * HID + gn] + gate[gn] * v;
        }
      }
    }
  }
}

// ---------------- q/k rmsnorm + rope preprocessing ----------------
__global__ __launch_bounds__(256) void qk_prep(const __bf16* __restrict__ src0, int rows0,
                                               const __bf16* __restrict__ src1, int off1,
                                               int total_rows, int q_rows,
                                               const float* __restrict__ pe,
                                               const float* __restrict__ qscale,
                                               const float* __restrict__ kscale,
                                               __bf16* __restrict__ qh, int q_stride,
                                               __bf16* __restrict__ kh, int k_stride)
{
  int wid = blockIdx.x * 4 + (threadIdx.x >> 6);
  int lane = threadIdx.x & 63;
  int r = wid / NHEAD, h = wid - (wid / NHEAD) * NHEAD;
  if (r >= total_rows) return;
  const __bf16* src = (r < rows0) ? (src0 + (size_t)r * 3072)
                                  : (src1 + (size_t)(r + off1) * 3072);
  const float* pep = pe + ((size_t)r * 64 + lane) * 4;
  float e00 = pep[0], e01 = pep[1], e10 = pep[2], e11 = pep[3];

  { // k
    const __bf16* p = src + HID + h * HD + 2 * lane;
    float a = (float)p[0], b = (float)p[1];
    float ss = a * a + b * b;
    #pragma unroll
    for (int msk = 32; msk; msk >>= 1) ss += __shfl_xor(ss, msk);
    float rinv = rsqrtf(ss * (1.0f / HD) + 1e-6f);
    a *= rinv * kscale[2 * lane]; b *= rinv * kscale[2 * lane + 1];
    float ra = e00 * a + e01 * b, rb = e10 * a + e11 * b;
    __bf16* o = kh + ((size_t)h * k_stride + r) * HD + 2 * lane;
    o[0] = (__bf16)ra; o[1] = (__bf16)rb;
  }
  if (r < q_rows) { // q (with folded softmax scale, exp2 domain)
    const __bf16* p = src + h * HD + 2 * lane;
    float a = (float)p[0], b = (float)p[1];
    float ss = a * a + b * b;
    #pragma unroll
    for (int msk = 32; msk; msk >>= 1) ss += __shfl_xor(ss, msk);
    float rinv = rsqrtf(ss * (1.0f / HD) + 1e-6f);
    a *= rinv * qscale[2 * lane]; b *= rinv * qscale[2 * lane + 1];
    float ra = (e00 * a + e01 * b) * QSCL, rb = (e10 * a + e11 * b) * QSCL;
    __bf16* o = qh + ((size_t)h * q_stride + r) * HD + 2 * lane;
    o[0] = (__bf16)ra; o[1] = (__bf16)rb;
  }
}

// ---------------- flash attention v3 ----------------
template<int GEN>
__global__ __launch_bounds__(512, 4) void attn_kernel(const __bf16* __restrict__ qh,
                                                      const __bf16* __restrict__ kh,
                                                      const __bf16* __restrict__ vA, int vA_stride,
                                                      const __bf16* __restrict__ vB, int vB_stride,
                                                      int v_boff, int v_split,
                                                      int Lq, int Lk, int q_stride, int k_stride,
                                                      int nqt,
                                                      __bf16* __restrict__ cat_out)
{
  const int tid = threadIdx.x, lane = tid & 63, wave = tid >> 6;
  const int quad = lane >> 4, l16 = lane & 15;
  const int qsub = wave >> 1, kg = wave & 1;

  int bid = blockIdx.x;
  if constexpr (GEN == 0) {
    int nb = gridDim.x;
    if ((nb & 7) == 0) {
      int per = nb >> 3;
      bid = (bid & 7) * per + (bid >> 3);
    }
  }
  const int head = bid / nqt, qt = bid - head * nqt;
  const int q0 = qt * 64 + qsub * 16;

  __shared__ __align__(16) unsigned char lds_raw[46080];
  __bf16 (*Ks)[136]     = (__bf16(*)[136])(lds_raw);            // [64][136]
  __bf16 (*Vt)[72]      = (__bf16(*)[72])(lds_raw + 17408);     // [128][72]
  __bf16 (*Ps)[16][40]  = (__bf16(*)[16][40])(lds_raw + 35840); // [8][16][40]
  float*  Of            = (float*)lds_raw;                      // merge alias [64][132]
  float (*Lml)[16][2]   = (float(*)[16][2])(lds_raw + 35840);   // merge alias

  const f32x4 fzero = {0.0f, 0.0f, 0.0f, 0.0f};
  const u32x4 uzero = {0, 0, 0, 0};

  bf16x8 ones;
  #pragma unroll
  for (int e = 0; e < 8; e++) ones[e] = (__bf16)1.0f;

  bf16x8 qf[4];
  {
    int qrow = q0 + l16;
    if (GEN == 0 || qrow < Lq) {
      const __bf16* qp = qh + ((size_t)head * q_stride + qrow) * HD + quad * 8;
      #pragma unroll
      for (int c = 0; c < 4; c++) qf[c] = *(const bf16x8*)(qp + c * 32);
    } else {
      #pragma unroll
      for (int c = 0; c < 4; c++) qf[c] = __builtin_bit_cast(bf16x8, uzero);
    }
  }
  f32x4 o[8];
  #pragma unroll
  for (int d = 0; d < 8; d++) o[d] = fzero;
  f32x4 l_acc = fzero;
  float m_r[4] = {-1e30f, -1e30f, -1e30f, -1e30f};

  const int krowA = tid >> 4, kcolA = (tid & 15) * 8;
  const int vdimA = tid >> 3, vkcA  = tid & 7;

  const __bf16* khb = kh + (size_t)head * k_stride * HD;
  const __bf16* vaB = vA + (size_t)head * HD * vA_stride;
  const __bf16* vbB = vB + (size_t)head * HD * vB_stride + v_boff;

  auto vload = [&](int dim, int kb) -> u32x4 {
    if constexpr (GEN == 0) {
      return *(const u32x4*)(vbB + (size_t)dim * vB_stride + kb);
    } else {
      u32x4 vd = uzero;
      if (kb < Lk) {
        if (kb + 8 <= v_split) {
          vd = *(const u32x4*)(vaB + (size_t)dim * vA_stride + kb);
        } else if (kb >= v_split && kb + 8 <= Lk) {
          vd = *(const u32x4*)(vbB + (size_t)dim * vB_stride + kb);
        } else {
          __bf16* ve = (__bf16*)&vd;
          #pragma unroll
          for (int e = 0; e < 8; e++) {
            int key = kb + e;
            if (key < Lk)
              ve[e] = (key < v_split) ? vaB[(size_t)dim * vA_stride + key]
                                      : vbB[(size_t)dim * vB_stride + key];
          }
        }
      }
      return vd;
    }
  };
  auto kload = [&](int kr, int col) -> u32x4 {
    if constexpr (GEN == 0) {
      return *(const u32x4*)(khb + (size_t)kr * HD + col);
    } else {
      return (kr < Lk) ? *(const u32x4*)(khb + (size_t)kr * HD + col) : uzero;
    }
  };

  u32x4 pk0, pk1, pv0, pv1;
  pk0 = kload(krowA, kcolA);
  pk1 = kload(krowA + 32, kcolA);
  pv0 = vload(vdimA, vkcA * 8);
  pv1 = vload(vdimA + 64, vkcA * 8);

  const int nkt = (Lk + 63) >> 6;
  for (int t = 0; t < nkt; ++t) {
    const int kt0 = t * 64;
    __syncthreads();
    *(u32x4*)&Ks[krowA][kcolA]      = pk0;
    *(u32x4*)&Ks[krowA + 32][kcolA] = pk1;
    *(u32x4*)&Vt[vdimA][vkcA * 8]      = pv0;
    *(u32x4*)&Vt[vdimA + 64][vkcA * 8] = pv1;
    if (t + 1 < nkt) {
      const int nt0 = kt0 + 64;
      pk0 = kload(nt0 + krowA, kcolA);
      pk1 = kload(nt0 + krowA + 32, kcolA);
      pv0 = vload(vdimA, nt0 + vkcA * 8);
      pv1 = vload(vdimA + 64, nt0 + vkcA * 8);
    }
    __syncthreads();

    f32x4 s[2];
    __builtin_amdgcn_s_setprio(1);
    #pragma unroll
    for (int nt = 0; nt < 2; nt++) {
      s[nt] = fzero;
      #pragma unroll
      for (int c = 0; c < 4; c++) {
        bf16x8 b = *(const bf16x8*)&Ks[kg * 32 + nt * 16 + l16][c * 32 + quad * 8];
        s[nt] = __builtin_amdgcn_mfma_f32_16x16x32_bf16(qf[c], b, s[nt], 0, 0, 0);
      }
      if constexpr (GEN != 0) {
        int kidx = kt0 + kg * 32 + nt * 16 + l16;
        if (kidx >= Lk) { s[nt][0] = -1e30f; s[nt][1] = -1e30f; s[nt][2] = -1e30f; s[nt][3] = -1e30f; }
      }
    }
    __builtin_amdgcn_s_setprio(0);

    float rm[4];
    #pragma unroll
    for (int r = 0; r < 4; r++) {
      float tmax = fmaxf(s[0][r], s[1][r]);
      tmax = fmaxf(tmax, __shfl_xor(tmax, 1));
      tmax = fmaxf(tmax, __shfl_xor(tmax, 2));
      tmax = fmaxf(tmax, __shfl_xor(tmax, 4));
      tmax = fmaxf(tmax, __shfl_xor(tmax, 8));
      rm[r] = tmax;
    }
    bool grow = (rm[0] > m_r[0] + 8.0f) || (rm[1] > m_r[1] + 8.0f)
             || (rm[2] > m_r[2] + 8.0f) || (rm[3] > m_r[3] + 8.0f);
    if (__any(grow)) {
      #pragma unroll
      for (int r = 0; r < 4; r++) {
        float mn = fmaxf(m_r[r], rm[r]);
        float alpha = exp2f(m_r[r] - mn);
        m_r[r] = mn;
        l_acc[r] *= alpha;
        #pragma unroll
        for (int d = 0; d < 8; d++) o[d][r] *= alpha;
      }
    }
    #pragma unroll
    for (int r = 0; r < 4; r++) {
      int prow = quad * 4 + r;
      Ps[wave][prow][l16]      = (__bf16)exp2f(s[0][r] - m_r[r]);
      Ps[wave][prow][16 + l16] = (__bf16)exp2f(s[1][r] - m_r[r]);
    }

    bf16x8 pf = *(const bf16x8*)&Ps[wave][l16][quad * 8];
    __builtin_amdgcn_s_setprio(1);
    l_acc = __builtin_amdgcn_mfma_f32_16x16x32_bf16(pf, ones, l_acc, 0, 0, 0);
    #pragma unroll
    for (int dt = 0; dt < 8; dt++) {
      bf16x8 bv = *(const bf16x8*)&Vt[dt * 16 + l16][kg * 32 + quad * 8];
      o[dt] = __builtin_amdgcn_mfma_f32_16x16x32_bf16(pf, bv, o[dt], 0, 0, 0);
    }
    __builtin_amdgcn_s_setprio(0);
  }

  __syncthreads();
  if (l16 == 0) {
    #pragma unroll
    for (int r = 0; r < 4; r++) {
      Lml[wave][quad * 4 + r][0] = m_r[r];
      Lml[wave][quad * 4 + r][1] = l_acc[r];
    }
  }
  __syncthreads();
  float a_self[4], inv_den[4];
  {
    const int other = wave ^ 1;
    #pragma unroll
    for (int r = 0; r < 4; r++) {
      int row = quad * 4 + r;
      float m_o = Lml[other][row][0], l_o = Lml[other][row][1];
      float M = fmaxf(m_r[r], m_o);
      float as = exp2f(m_r[r] - M), ao = exp2f(m_o - M);
      a_self[r] = as;
      inv_den[r] = 1.0f / (as * l_acc[r] + ao * l_o);
    }
  }
  if (kg == 0) {
    #pragma unroll
    for (int d = 0; d < 8; d++)
      #pragma unroll
      for (int r = 0; r < 4; r++)
        Of[(size_t)(qsub * 16 + quad * 4 + r) * 132 + d * 16 + l16] = o[d][r] * a_self[r];
  }
  __syncthreads();
  if (kg == 1) {
    #pragma unroll
    for (int r = 0; r < 4; r++) {
      int qrow = q0 + quad * 4 + r;
      if (qrow >= Lq) continue;
      #pragma unroll
      for (int d = 0; d < 8; d++) {
        float v = Of[(size_t)(qsub * 16 + quad * 4 + r) * 132 + d * 16 + l16]
                  + o[d][r] * a_self[r];
        cat_out[(size_t)qrow * CATK + head * HD + d * 16 + l16] = (__bf16)(v * inv_den[r]);
      }
    }
  }
}

// ---------------- launch ----------------
extern "C" void kernel_launch(void* const* d_in, const int* in_sizes, int n_in,
                              void* d_out, int out_size, void* d_ws, size_t ws_size,
                              hipStream_t stream)
{
  const float* x   = (const float*)d_in[0];
  const float* con = (const float*)d_in[1];
  const float* vec = (const float*)d_in[2];
  const float* pe  = (const float*)d_in[3];
  const float* cpe = (const float*)d_in[4];
  const float* w1  = (const float*)d_in[5];
  const float* b1  = (const float*)d_in[6];
  const float* w2  = (const float*)d_in[7];
  const float* b2  = (const float*)d_in[8];
  const float* qsc = (const float*)d_in[9];
  const float* ksc = (const float*)d_in[10];
  const float* mw  = (const float*)d_in[11];
  const float* mb  = (const float*)d_in[12];
  float* out = (float*)d_out;

  char* ws = (char*)d_ws;
  float*  mvec = (float*)(ws + OFF_MVEC);
  __bf16* w1b  = (__bf16*)(ws + OFF_W1B);
  __bf16* w2b  = (__bf16*)(ws + OFF_W2B);
  __bf16* xm1  = (__bf16*)(ws + OFF_XM1);
  __bf16* qh1  = (__bf16*)(ws + OFF_QH1);
  __bf16* qkv1 = (__bf16*)(ws + OFF_QKV1);
  __bf16* kh1  = (__bf16*)(ws + OFF_KH1);
  __bf16* vh1  = (__bf16*)(ws + OFF_VH1);
  __bf16* cat1 = (__bf16*)(ws + OFF_CAT1);
  __bf16* xm2  = (__bf16*)(ws + OFF_XM2);
  __bf16* qkv2 = (__bf16*)(ws + OFF_QKV2);
  __bf16* vh2s = (__bf16*)(ws + OFF_VH2S);
  __bf16* qh2  = (__bf16*)(ws + OFF_QH2);
  __bf16* kh2  = (__bf16*)(ws + OFF_KH2);
  __bf16* cat2 = (__bf16*)(ws + OFF_CAT2);

  // weights -> bf16
  f2b_kernel<<<16128, 256, 0, stream>>>(w1, w1b, (NQKV * HID) / 4);
  f2b_kernel<<<11520, 256, 0, stream>>>(w2, w2b, (HID * CATK) / 4);
  // modulation vector
  mod_kernel<<<1152, 256, 0, stream>>>(vec, mw, mb, mvec);

  // ---- block 1 ----
  ln_mod_kernel<<<LX, 256, 0, stream>>>(x, mvec, xm1);
  gemm256<0><<<dim3(NQKV / 256, LX / 256), 512, 0, stream>>>(
      xm1, w1b, LX, HID, b1, qkv1, cat1, vh1, LX, nullptr, nullptr, nullptr);
  qk_prep<<<(LX * NHEAD) / 4, 256, 0, stream>>>(
      qkv1, LX, qkv1, 0, LX, LX, pe, qsc, ksc, qh1, LX, kh1, LX);
  attn_kernel<0><<<NHEAD * (LX / 64), 512, 0, stream>>>(
      qh1, kh1, vh1, LX, vh1, LX, 0, 0, LX, LX, LX, LX, LX / 64, cat1);
  gemm256<1><<<dim3(HID / 256, LX / 256), 512, 0, stream>>>(
      cat1, w2b, LX, CATK, b2, nullptr, nullptr, nullptr, 0, x, mvec + 3072, out);

  // ---- block 2 (only 20 concept queries matter; k/v of image rows reused from block 1) ----
  ln_mod_kernel<<<NCON, 256, 0, stream>>>(con, mvec, xm2);
  gemm_bt<0><<<dim3(NQKV / 128, 1), 256, 0, stream>>>(
      xm2, w1b, NCON, HID, b1, qkv2, cat2, vh2s, 32, nullptr, nullptr, nullptr);
  qk_prep<<<(LC2 * NHEAD + 3) / 4, 256, 0, stream>>>(
      qkv2, NCON, qkv1, 236, LC2, NCON, cpe, qsc, ksc, qh2, 64, kh2, LC2);
  attn_kernel<1><<<NHEAD, 512, 0, stream>>>(
      qh2, kh2, vh2s, 32, vh1, LX, 236, NCON, NCON, LC2, 64, LC2, 1, cat2);
  gemm_bt<1><<<dim3(HID / 128, 1), 256, 0, stream>>>(
      cat2, w2b, NCON, CATK, b2, nullptr, nullptr, nullptr, 0, con, mvec + 3072,
      out + (size_t)LX * HID);
}

// Round 3
// 1319.065 us; speedup vs baseline: 1.0983x; 1.0983x over previous
//
#include <hip/hip_runtime.h>
#include <cstdint>
#include <cstddef>

typedef float        f32x4  __attribute__((ext_vector_type(4)));
typedef __bf16       bf16x8 __attribute__((ext_vector_type(8)));
typedef unsigned int u32x4  __attribute__((ext_vector_type(4)));
typedef unsigned int u32x2  __attribute__((ext_vector_type(2)));

// ---------------- problem dims ----------------
static constexpr int HID   = 1536;
static constexpr int NHEAD = 12;
static constexpr int HD    = 128;
static constexpr int NQKV  = 10752;   // 3*HID + 4*HID
static constexpr int CATK  = 7680;    // HID + 4*HID
static constexpr int LX    = 4352;    // text 256 + 4096 image
static constexpr int LC2   = 4116;    // 20 concepts + 4096 image
static constexpr int NCON  = 20;

// q pre-scale: 1/sqrt(128) * log2(e)  (softmax computed in exp2 domain)
static constexpr float QSCL = 0.08838834764831845f * 1.4426950408889634f;
// fixed softmax shift: rmsnorm'd q,k with unit scales bound |S_exp2| <=
// sqrt(128)*log2e = 16.34 << 24. P = exp2(S-24) in bf16 keeps full 8-bit
// relative precision (bf16 min normal 2^-126); l,O accumulate in f32.
static constexpr float SHIFT = 24.0f;

// ---------------- workspace layout (bytes) ----------------
static constexpr size_t OFF_MVEC = 0;                          // 4608 f32
static constexpr size_t OFF_W1B  = 18432;                      // 10752x1536 bf16
static constexpr size_t OFF_W2B  = OFF_W1B  + 33030144ull;     // 1536x7680 bf16
static constexpr size_t OFF_XM1  = OFF_W2B  + 23592960ull;     // 4352x1536 bf16 (later aliased by qh1)
static constexpr size_t OFF_QH1  = OFF_XM1;                    // [12][4352][128] bf16
static constexpr size_t OFF_QKV1 = OFF_XM1  + 13369344ull;     // 4352x3072 bf16 (q,k raw)
static constexpr size_t OFF_KH1  = OFF_QKV1 + 26738688ull;     // [12][4352][128]
static constexpr size_t OFF_VH1  = OFF_KH1  + 13369344ull;     // [12][128][4352] (transposed)
static constexpr size_t OFF_CAT1 = OFF_VH1  + 13369344ull;     // 4352x7680 bf16
// block-2 scratch aliased inside cat1 (cat1 dead after GEMM2 of block 1):
static constexpr size_t OFF_XM2  = OFF_CAT1;                   // 64x1536 bf16
static constexpr size_t OFF_QKV2 = OFF_XM2  + 196608ull;       // 32x3072 bf16
static constexpr size_t OFF_VH2S = OFF_QKV2 + 196608ull;       // [12][128][32]
static constexpr size_t OFF_QH2  = OFF_VH2S + 98304ull;        // [12][64][128]
static constexpr size_t OFF_KH2  = OFF_QH2  + 196608ull;       // [12][4116][128]
static constexpr size_t OFF_CAT2 = OFF_KH2  + 12644352ull;     // 32x7680 bf16
// total required: OFF_CAT1 + 66846720 = 190,334,976 bytes

// async global->LDS, 16B per lane. LDS dest must be wave-uniform base; HW
// writes base + lane*16 (m104). Global src is per-lane.
__device__ __forceinline__ void gload_lds16(const void* g, void* l)
{
  __builtin_amdgcn_global_load_lds(
      (const __attribute__((address_space(1))) unsigned int*)g,
      (__attribute__((address_space(3))) unsigned int*)l, 16, 0, 0);
}

// raw phase barrier: NO waitcnt drain. Every ds_read is consumed by an MFMA
// before its wave reaches the next barrier (compiler inserts exact lgkmcnt),
// so barrier semantics alone give WAR safety; ds_read latency overlaps the
// barrier wait instead of serializing before it.
#define PHASE_BAR() asm volatile("s_barrier" ::: "memory")

// ---------------- small kernels ----------------

__global__ __launch_bounds__(256) void f2b_kernel(const float* __restrict__ in,
                                                  __bf16* __restrict__ out, int n4)
{
  int i = blockIdx.x * 256 + threadIdx.x;
  if (i >= n4) return;
  f32x4 v = *((const f32x4*)in + i);
  union { __bf16 h[4]; u32x2 u; } cv;
  cv.h[0] = (__bf16)v[0]; cv.h[1] = (__bf16)v[1];
  cv.h[2] = (__bf16)v[2]; cv.h[3] = (__bf16)v[3];
  *((u32x2*)out + i) = cv.u;
}

// m = silu(vec) @ mod_w.T + mod_b   (one wave per output)
__global__ __launch_bounds__(256) void mod_kernel(const float* __restrict__ vec,
                                                  const float* __restrict__ mod_w,
                                                  const float* __restrict__ mod_b,
                                                  float* __restrict__ m)
{
  int o = blockIdx.x * 4 + (threadIdx.x >> 6);
  int lane = threadIdx.x & 63;
  float s = 0.0f;
  for (int k = lane; k < HID; k += 64) {
    float v = vec[k];
    float sv = v / (1.0f + expf(-v));
    s += sv * mod_w[(size_t)o * HID + k];
  }
  #pragma unroll
  for (int msk = 32; msk; msk >>= 1) s += __shfl_xor(s, msk);
  if (lane == 0) m[o] = s + mod_b[o];
}

__device__ __forceinline__ float block_sum256(float v, float* red)
{
  #pragma unroll
  for (int msk = 32; msk; msk >>= 1) v += __shfl_xor(v, msk);
  int w = threadIdx.x >> 6;
  if ((threadIdx.x & 63) == 0) red[w] = v;
  __syncthreads();
  float s = red[0] + red[1] + red[2] + red[3];
  __syncthreads();
  return s;
}

// xm = (1+scale)*layernorm(x) + shift, bf16 out. one block per row.
__global__ __launch_bounds__(256) void ln_mod_kernel(const float* __restrict__ x,
                                                     const float* __restrict__ mvec,
                                                     __bf16* __restrict__ out)
{
  __shared__ float red[4];
  size_t row = blockIdx.x;
  const float* xr = x + row * HID;
  float v[6]; float s = 0.0f;
  #pragma unroll
  for (int i = 0; i < 6; i++) { v[i] = xr[threadIdx.x + i * 256]; s += v[i]; }
  float mu = block_sum256(s, red) * (1.0f / HID);
  float s2 = 0.0f;
  #pragma unroll
  for (int i = 0; i < 6; i++) { float d = v[i] - mu; s2 += d * d; }
  float var = block_sum256(s2, red) * (1.0f / HID);
  float rinv = rsqrtf(var + 1e-6f);
  #pragma unroll
  for (int i = 0; i < 6; i++) {
    int h = threadIdx.x + i * 256;
    float xm = (v[i] - mu) * rinv;
    xm = (1.0f + mvec[HID + h]) * xm + mvec[h];
    out[row * HID + h] = (__bf16)xm;
  }
}

// ---------------- 256x256 8-phase GEMM (B^T layout): C[m,n]=sum_k A[m,k]B[n,k]
// 512 threads = 8 waves (2M x 4N), per-wave output 128x64, BK=64.
// LDS 128 KiB: As/Bs[2][256][64] double-buffered (2-tile depth).
// T2 swizzle via pre-swizzled global source + XOR'd ds_read col.
// T3/T4: 4 phases/K-tile, raw s_barrier boundaries (no lgkm drain — the
//   compiler places exact lgkmcnt(N) after the barrier, overlapping read
//   latency with barrier wait); counted vmcnt(8) once per tile.
// T5: setprio(1) around each 16-MFMA cluster.
template<int MODE>
__global__ __launch_bounds__(512, 2) void gemm256(const __bf16* __restrict__ A,
                                                  const __bf16* __restrict__ B,
                                                  int M, int K,
                                                  const float* __restrict__ bias,
                                                  __bf16* __restrict__ qkv_out,
                                                  __bf16* __restrict__ cat_out,
                                                  __bf16* __restrict__ vh_out, int vkeys,
                                                  const float* __restrict__ res,
                                                  const float* __restrict__ gate,
                                                  float* __restrict__ out)
{
  const int tid = threadIdx.x;
  const int lane = tid & 63, wave = tid >> 6;
  const int quad = lane >> 4, l16 = lane & 15;
  const int wmh = wave >> 2;            // M half (0/1) -> rows wmh*128..+127
  const int wnq = wave & 3;             // N quarter    -> cols wnq*64..+63
  const int m0 = blockIdx.y * 256, n0 = blockIdx.x * 256;
  const int swz = (l16 & 4) ? 16 : 0;   // read-side XOR (row&4 == l16&4)

  __shared__ __bf16 As[2][256][64];
  __shared__ __bf16 Bs[2][256][64];

  const f32x4 fzero = {0.0f, 0.0f, 0.0f, 0.0f};
  f32x4 acc[8][4];
  #pragma unroll
  for (int i = 0; i < 8; i++)
    #pragma unroll
    for (int j = 0; j < 4; j++) acc[i][j] = fzero;

  // staging: wave w owns A rows [w*32,+32) and B rows [w*32,+32); 4 issues
  // each (8 rows x 128B per issue). source col pre-swizzled so LDS ends up
  // st_16x32-swizzled while gload_lds dest stays linear.
  const int srow = lane >> 3;
  const int scol = ((lane & 7) * 8) ^ ((lane & 32) ? 16 : 0);
  const __bf16* Ag = A + (size_t)(m0 + wave * 32 + srow) * K + scol;
  const __bf16* Bg = B + (size_t)(n0 + wave * 32 + srow) * K + scol;

  auto stageA = [&](int buf, int k) {
    #pragma unroll
    for (int j = 0; j < 4; j++)
      gload_lds16(Ag + (size_t)(j * 8) * K + k, &As[buf][wave * 32 + j * 8][0]);
  };
  auto stageB = [&](int buf, int k) {
    #pragma unroll
    for (int j = 0; j < 4; j++)
      gload_lds16(Bg + (size_t)(j * 8) * K + k, &Bs[buf][wave * 32 + j * 8][0]);
  };

  const int NT = K >> 6;
  // prologue: tiles 0 and 1. S(0)=first 8 issues, S(1)=next 8.
  stageB(0, 0);  stageA(0, 0);
  stageB(1, 64); stageA(1, 64);
  asm volatile("s_waitcnt vmcnt(8)" ::: "memory");   // own S(0) landed
  PHASE_BAR();                                       // => everyone's S(0) landed

  for (int t = 0; t < NT; ++t) {
    const int b = t & 1;
    const int kn = (t + 2) << 6;
    bf16x8 aM[4][2], bN0[2][2], bN1[2][2];

    // ---- phase 0: quadrant (M0,N0); 12 ds_reads ----
    #pragma unroll
    for (int f = 0; f < 4; f++)
      #pragma unroll
      for (int kk = 0; kk < 2; kk++)
        aM[f][kk] = *(const bf16x8*)&As[b][wmh * 128 + f * 16 + l16][(kk * 32 + quad * 8) ^ swz];
    #pragma unroll
    for (int g = 0; g < 2; g++)
      #pragma unroll
      for (int kk = 0; kk < 2; kk++)
        bN0[g][kk] = *(const bf16x8*)&Bs[b][wnq * 64 + g * 16 + l16][(kk * 32 + quad * 8) ^ swz];
    PHASE_BAR();
    __builtin_amdgcn_s_setprio(1);
    #pragma unroll
    for (int f = 0; f < 4; f++)
      #pragma unroll
      for (int g = 0; g < 2; g++)
        #pragma unroll
        for (int kk = 0; kk < 2; kk++)
          acc[f][g] = __builtin_amdgcn_mfma_f32_16x16x32_bf16(aM[f][kk], bN0[g][kk], acc[f][g], 0, 0, 0);
    __builtin_amdgcn_s_setprio(0);
    PHASE_BAR();

    // ---- phase 1: (M0,N1); 4 ds_reads ----
    #pragma unroll
    for (int g = 0; g < 2; g++)
      #pragma unroll
      for (int kk = 0; kk < 2; kk++)
        bN1[g][kk] = *(const bf16x8*)&Bs[b][wnq * 64 + 32 + g * 16 + l16][(kk * 32 + quad * 8) ^ swz];
    PHASE_BAR();
    __builtin_amdgcn_s_setprio(1);
    #pragma unroll
    for (int f = 0; f < 4; f++)
      #pragma unroll
      for (int g = 0; g < 2; g++)
        #pragma unroll
        for (int kk = 0; kk < 2; kk++)
          acc[f][2 + g] = __builtin_amdgcn_mfma_f32_16x16x32_bf16(aM[f][kk], bN1[g][kk], acc[f][2 + g], 0, 0, 0);
    __builtin_amdgcn_s_setprio(0);
    PHASE_BAR();

    // ---- phase 2: (M1,N1); 8 ds_reads; stage B(t+2) (B region dead) ----
    #pragma unroll
    for (int f = 0; f < 4; f++)
      #pragma unroll
      for (int kk = 0; kk < 2; kk++)
        aM[f][kk] = *(const bf16x8*)&As[b][wmh * 128 + 64 + f * 16 + l16][(kk * 32 + quad * 8) ^ swz];
    if (t + 2 < NT) stageB(b, kn);
    PHASE_BAR();
    __builtin_amdgcn_s_setprio(1);
    #pragma unroll
    for (int f = 0; f < 4; f++)
      #pragma unroll
      for (int g = 0; g < 2; g++)
        #pragma unroll
        for (int kk = 0; kk < 2; kk++)
          acc[4 + f][2 + g] = __builtin_amdgcn_mfma_f32_16x16x32_bf16(aM[f][kk], bN1[g][kk], acc[4 + f][2 + g], 0, 0, 0);
    __builtin_amdgcn_s_setprio(0);
    PHASE_BAR();

    // ---- phase 3: (M1,N0); stage A(t+2) (A region dead); tile-boundary vmcnt ----
    if (t + 2 < NT) stageA(b, kn);
    PHASE_BAR();
    __builtin_amdgcn_s_setprio(1);
    #pragma unroll
    for (int f = 0; f < 4; f++)
      #pragma unroll
      for (int g = 0; g < 2; g++)
        #pragma unroll
        for (int kk = 0; kk < 2; kk++)
          acc[4 + f][g] = __builtin_amdgcn_mfma_f32_16x16x32_bf16(aM[f][kk], bN0[g][kk], acc[4 + f][g], 0, 0, 0);
    __builtin_amdgcn_s_setprio(0);
    if (t + 1 < NT) {
      if (t + 2 < NT) asm volatile("s_waitcnt vmcnt(8)" ::: "memory");  // S(t+1) landed, S(t+2) in flight
      else            asm volatile("s_waitcnt vmcnt(0)" ::: "memory");  // final drain
    }
    PHASE_BAR();
  }

  // ---- epilogue ----
  #pragma unroll
  for (int mf = 0; mf < 8; mf++) {
    #pragma unroll
    for (int r = 0; r < 4; r++) {
      int gm = m0 + wmh * 128 + mf * 16 + quad * 4 + r;
      if (gm >= M) continue;
      #pragma unroll
      for (int nf = 0; nf < 4; nf++) {
        int gn = n0 + wnq * 64 + nf * 16 + l16;
        float v = acc[mf][nf][r] + bias[gn];
        if constexpr (MODE == 0) {
          if (gn < 3072) {                 // q,k raw
            qkv_out[(size_t)gm * 3072 + gn] = (__bf16)v;
          } else if (gn < 4608) {          // v -> transposed [head*128+d][key]
            vh_out[(size_t)(gn - 3072) * vkeys + gm] = (__bf16)v;
          } else {                         // mlp -> gelu -> cat cols [1536,7680)
            float g = 0.5f * v * (1.0f + tanhf(0.7978845608028654f * (v + 0.044715f * v * v * v)));
            cat_out[(size_t)gm * CATK + (gn - 3072)] = (__bf16)g;
          }
        } else {
          out[(size_t)gm * HID + gn] = res[(size_t)gm * HID + gn] + gate[gn] * v;
        }
      }
    }
  }
}

// ---------------- legacy 128x128 GEMM (block-2 small dispatches, M=20) ----
template<int MODE>
__global__ __launch_bounds__(256) void gemm_bt(const __bf16* __restrict__ A,
                                               const __bf16* __restrict__ B,
                                               int M, int K,
                                               const float* __restrict__ bias,
                                               __bf16* __restrict__ qkv_out,
                                               __bf16* __restrict__ cat_out,
                                               __bf16* __restrict__ vh_out, int vkeys,
                                               const float* __restrict__ res,
                                               const float* __restrict__ gate,
                                               float* __restrict__ out)
{
  const int tid = threadIdx.x;
  const int lane = tid & 63, wave = tid >> 6;
  const int quad = lane >> 4, l16 = lane & 15;
  const int m0 = blockIdx.y * 128, n0 = blockIdx.x * 128;
  const int wm = (wave & 1) * 64, wn = (wave >> 1) * 64;

  __shared__ __bf16 As[128][64];
  __shared__ __bf16 Bs[128][64];

  const f32x4 fzero = {0.0f, 0.0f, 0.0f, 0.0f};
  f32x4 acc[4][4];
  #pragma unroll
  for (int i = 0; i < 4; i++)
    #pragma unroll
    for (int j = 0; j < 4; j++) acc[i][j] = fzero;

  const int srow = lane >> 3;
  const int scol = (lane & 7) * 8;
  const int rbase = wave * 32 + srow;
  const __bf16* Ab = A + (size_t)(m0 + rbase) * K + scol;
  const __bf16* Bb = B + (size_t)(n0 + rbase) * K + scol;

  for (int k0 = 0; k0 < K; k0 += 64) {
    __syncthreads();
    #pragma unroll
    for (int j = 0; j < 4; j++) {
      gload_lds16(Ab + (size_t)(j * 8) * K + k0, &As[wave * 32 + j * 8][0]);
      gload_lds16(Bb + (size_t)(j * 8) * K + k0, &Bs[wave * 32 + j * 8][0]);
    }
    __syncthreads();
    #pragma unroll
    for (int kk = 0; kk < 64; kk += 32) {
      bf16x8 af[4], bfr[4];
      #pragma unroll
      for (int i = 0; i < 4; i++) af[i]  = *(const bf16x8*)&As[wm + i * 16 + l16][kk + quad * 8];
      #pragma unroll
      for (int j = 0; j < 4; j++) bfr[j] = *(const bf16x8*)&Bs[wn + j * 16 + l16][kk + quad * 8];
      #pragma unroll
      for (int i = 0; i < 4; i++)
        #pragma unroll
        for (int j = 0; j < 4; j++)
          acc[i][j] = __builtin_amdgcn_mfma_f32_16x16x32_bf16(af[i], bfr[j], acc[i][j], 0, 0, 0);
    }
  }

  #pragma unroll
  for (int i = 0; i < 4; i++) {
    #pragma unroll
    for (int r = 0; r < 4; r++) {
      int gm = m0 + wm + i * 16 + quad * 4 + r;
      if (gm >= M) continue;
      #pragma unroll
      for (int j = 0; j < 4; j++) {
        int gn = n0 + wn + j * 16 + l16;
        float v = acc[i][j][r] + bias[gn];
        if constexpr (MODE == 0) {
          if (gn < 3072) {
            qkv_out[(size_t)gm * 3072 + gn] = (__bf16)v;
          } else if (gn < 4608) {
            vh_out[(size_t)(gn - 3072) * vkeys + gm] = (__bf16)v;
          } else {
            float g = 0.5f * v * (1.0f + tanhf(0.7978845608028654f * (v + 0.044715f * v * v * v)));
            cat_out[(size_t)gm * CATK + (gn - 3072)] = (__bf16)g;
          }
        } else {
          out[(size_t)gm * HID + gn] = res[(size_t)gm * HID + gn] + gate[gn] * v;
        }
      }
    }
  }
}

// ---------------- q/k rmsnorm + rope preprocessing ----------------
__global__ __launch_bounds__(256) void qk_prep(const __bf16* __restrict__ src0, int rows0,
                                               const __bf16* __restrict__ src1, int off1,
                                               int total_rows, int q_rows,
                                               const float* __restrict__ pe,
                                               const float* __restrict__ qscale,
                                               const float* __restrict__ kscale,
                                               __bf16* __restrict__ qh, int q_stride,
                                               __bf16* __restrict__ kh, int k_stride)
{
  int wid = blockIdx.x * 4 + (threadIdx.x >> 6);
  int lane = threadIdx.x & 63;
  int r = wid / NHEAD, h = wid - (wid / NHEAD) * NHEAD;
  if (r >= total_rows) return;
  const __bf16* src = (r < rows0) ? (src0 + (size_t)r * 3072)
                                  : (src1 + (size_t)(r + off1) * 3072);
  const float* pep = pe + ((size_t)r * 64 + lane) * 4;
  float e00 = pep[0], e01 = pep[1], e10 = pep[2], e11 = pep[3];

  { // k
    const __bf16* p = src + HID + h * HD + 2 * lane;
    float a = (float)p[0], b = (float)p[1];
    float ss = a * a + b * b;
    #pragma unroll
    for (int msk = 32; msk; msk >>= 1) ss += __shfl_xor(ss, msk);
    float rinv = rsqrtf(ss * (1.0f / HD) + 1e-6f);
    a *= rinv * kscale[2 * lane]; b *= rinv * kscale[2 * lane + 1];
    float ra = e00 * a + e01 * b, rb = e10 * a + e11 * b;
    __bf16* o = kh + ((size_t)h * k_stride + r) * HD + 2 * lane;
    o[0] = (__bf16)ra; o[1] = (__bf16)rb;
  }
  if (r < q_rows) { // q (with folded softmax scale, exp2 domain)
    const __bf16* p = src + h * HD + 2 * lane;
    float a = (float)p[0], b = (float)p[1];
    float ss = a * a + b * b;
    #pragma unroll
    for (int msk = 32; msk; msk >>= 1) ss += __shfl_xor(ss, msk);
    float rinv = rsqrtf(ss * (1.0f / HD) + 1e-6f);
    a *= rinv * qscale[2 * lane]; b *= rinv * qscale[2 * lane + 1];
    float ra = (e00 * a + e01 * b) * QSCL, rb = (e10 * a + e11 * b) * QSCL;
    __bf16* o = qh + ((size_t)h * q_stride + r) * HD + 2 * lane;
    o[0] = (__bf16)ra; o[1] = (__bf16)rb;
  }
}

// ---------------- flash attention, fixed-shift softmax ----------------
// rmsnorm bounds |S_exp2| <= 16.34, so no online max tracking: P=exp2(S-24)
// in bf16; O,l accumulate in f32 (MFMA); one normalization at the end.
// Merge of the two kg halves is a plain sum.
template<int GEN>
__global__ __launch_bounds__(512, 4) void attn_kernel(const __bf16* __restrict__ qh,
                                                      const __bf16* __restrict__ kh,
                                                      const __bf16* __restrict__ vA, int vA_stride,
                                                      const __bf16* __restrict__ vB, int vB_stride,
                                                      int v_boff, int v_split,
                                                      int Lq, int Lk, int q_stride, int k_stride,
                                                      int nqt,
                                                      __bf16* __restrict__ cat_out)
{
  const int tid = threadIdx.x, lane = tid & 63, wave = tid >> 6;
  const int quad = lane >> 4, l16 = lane & 15;
  const int qsub = wave >> 1, kg = wave & 1;

  int bid = blockIdx.x;
  if constexpr (GEN == 0) {
    int nb = gridDim.x;
    if ((nb & 7) == 0) {
      int per = nb >> 3;
      bid = (bid & 7) * per + (bid >> 3);
    }
  }
  const int head = bid / nqt, qt = bid - head * nqt;
  const int q0 = qt * 64 + qsub * 16;

  __shared__ __align__(16) unsigned char lds_raw[46080];
  __bf16 (*Ks)[136]     = (__bf16(*)[136])(lds_raw);            // [64][136]
  __bf16 (*Vt)[72]      = (__bf16(*)[72])(lds_raw + 17408);     // [128][72]
  __bf16 (*Ps)[16][40]  = (__bf16(*)[16][40])(lds_raw + 35840); // [8][16][40]
  float*  Of            = (float*)lds_raw;                      // merge alias [64][132]
  float*  Lf            = (float*)(lds_raw + 35840);            // merge alias [8][16]

  const f32x4 fzero = {0.0f, 0.0f, 0.0f, 0.0f};
  const u32x4 uzero = {0, 0, 0, 0};

  bf16x8 ones;
  #pragma unroll
  for (int e = 0; e < 8; e++) ones[e] = (__bf16)1.0f;

  bf16x8 qf[4];
  {
    int qrow = q0 + l16;
    if (GEN == 0 || qrow < Lq) {
      const __bf16* qp = qh + ((size_t)head * q_stride + qrow) * HD + quad * 8;
      #pragma unroll
      for (int c = 0; c < 4; c++) qf[c] = *(const bf16x8*)(qp + c * 32);
    } else {
      #pragma unroll
      for (int c = 0; c < 4; c++) qf[c] = __builtin_bit_cast(bf16x8, uzero);
    }
  }
  f32x4 o[8];
  #pragma unroll
  for (int d = 0; d < 8; d++) o[d] = fzero;
  f32x4 l_acc = fzero;

  const int krowA = tid >> 4, kcolA = (tid & 15) * 8;
  const int vdimA = tid >> 3, vkcA  = tid & 7;

  const __bf16* khb = kh + (size_t)head * k_stride * HD;
  const __bf16* vaB = vA + (size_t)head * HD * vA_stride;
  const __bf16* vbB = vB + (size_t)head * HD * vB_stride + v_boff;

  auto vload = [&](int dim, int kb) -> u32x4 {
    if constexpr (GEN == 0) {
      return *(const u32x4*)(vbB + (size_t)dim * vB_stride + kb);
    } else {
      u32x4 vd = uzero;
      if (kb < Lk) {
        if (kb + 8 <= v_split) {
          vd = *(const u32x4*)(vaB + (size_t)dim * vA_stride + kb);
        } else if (kb >= v_split && kb + 8 <= Lk) {
          vd = *(const u32x4*)(vbB + (size_t)dim * vB_stride + kb);
        } else {
          __bf16* ve = (__bf16*)&vd;
          #pragma unroll
          for (int e = 0; e < 8; e++) {
            int key = kb + e;
            if (key < Lk)
              ve[e] = (key < v_split) ? vaB[(size_t)dim * vA_stride + key]
                                      : vbB[(size_t)dim * vB_stride + key];
          }
        }
      }
      return vd;
    }
  };
  auto kload = [&](int kr, int col) -> u32x4 {
    if constexpr (GEN == 0) {
      return *(const u32x4*)(khb + (size_t)kr * HD + col);
    } else {
      return (kr < Lk) ? *(const u32x4*)(khb + (size_t)kr * HD + col) : uzero;
    }
  };

  u32x4 pk0, pk1, pv0, pv1;
  pk0 = kload(krowA, kcolA);
  pk1 = kload(krowA + 32, kcolA);
  pv0 = vload(vdimA, vkcA * 8);
  pv1 = vload(vdimA + 64, vkcA * 8);

  const int nkt = (Lk + 63) >> 6;
  for (int t = 0; t < nkt; ++t) {
    const int kt0 = t * 64;
    __syncthreads();
    *(u32x4*)&Ks[krowA][kcolA]      = pk0;
    *(u32x4*)&Ks[krowA + 32][kcolA] = pk1;
    *(u32x4*)&Vt[vdimA][vkcA * 8]      = pv0;
    *(u32x4*)&Vt[vdimA + 64][vkcA * 8] = pv1;
    if (t + 1 < nkt) {
      const int nt0 = kt0 + 64;
      pk0 = kload(nt0 + krowA, kcolA);
      pk1 = kload(nt0 + krowA + 32, kcolA);
      pv0 = vload(vdimA, nt0 + vkcA * 8);
      pv1 = vload(vdimA + 64, nt0 + vkcA * 8);
    }
    __syncthreads();

    f32x4 s[2];
    __builtin_amdgcn_s_setprio(1);
    #pragma unroll
    for (int nt = 0; nt < 2; nt++) {
      s[nt] = fzero;
      #pragma unroll
      for (int c = 0; c < 4; c++) {
        bf16x8 b = *(const bf16x8*)&Ks[kg * 32 + nt * 16 + l16][c * 32 + quad * 8];
        s[nt] = __builtin_amdgcn_mfma_f32_16x16x32_bf16(qf[c], b, s[nt], 0, 0, 0);
      }
      if constexpr (GEN != 0) {
        int kidx = kt0 + kg * 32 + nt * 16 + l16;
        if (kidx >= Lk) { s[nt][0] = -1e30f; s[nt][1] = -1e30f; s[nt][2] = -1e30f; s[nt][3] = -1e30f; }
      }
    }
    __builtin_amdgcn_s_setprio(0);

    // fixed-shift P (no max tracking, no rescale)
    #pragma unroll
    for (int r = 0; r < 4; r++) {
      int prow = quad * 4 + r;
      Ps[wave][prow][l16]      = (__bf16)exp2f(s[0][r] - SHIFT);
      Ps[wave][prow][16 + l16] = (__bf16)exp2f(s[1][r] - SHIFT);
    }
    // no barrier: Ps is wave-local (intra-wave DS ordering + compiler lgkmcnt)

    bf16x8 pf = *(const bf16x8*)&Ps[wave][l16][quad * 8];
    __builtin_amdgcn_s_setprio(1);
    l_acc = __builtin_amdgcn_mfma_f32_16x16x32_bf16(pf, ones, l_acc, 0, 0, 0);
    #pragma unroll
    for (int dt = 0; dt < 8; dt++) {
      bf16x8 bv = *(const bf16x8*)&Vt[dt * 16 + l16][kg * 32 + quad * 8];
      o[dt] = __builtin_amdgcn_mfma_f32_16x16x32_bf16(pf, bv, o[dt], 0, 0, 0);
    }
    __builtin_amdgcn_s_setprio(0);
  }

  // ---- merge the two kg halves: plain sums ----
  __syncthreads();                         // all tiles done; LDS reusable
  if (l16 == 0) {
    #pragma unroll
    for (int r = 0; r < 4; r++) Lf[wave * 16 + quad * 4 + r] = l_acc[r];
  }
  __syncthreads();
  float inv_den[4];
  #pragma unroll
  for (int r = 0; r < 4; r++)
    inv_den[r] = 1.0f / (l_acc[r] + Lf[(wave ^ 1) * 16 + quad * 4 + r]);
  if (kg == 0) {
    #pragma unroll
    for (int d = 0; d < 8; d++)
      #pragma unroll
      for (int r = 0; r < 4; r++)
        Of[(size_t)(qsub * 16 + quad * 4 + r) * 132 + d * 16 + l16] = o[d][r];
  }
  __syncthreads();
  if (kg == 1) {
    #pragma unroll
    for (int r = 0; r < 4; r++) {
      int qrow = q0 + quad * 4 + r;
      if (qrow >= Lq) continue;
      #pragma unroll
      for (int d = 0; d < 8; d++) {
        float v = Of[(size_t)(qsub * 16 + quad * 4 + r) * 132 + d * 16 + l16] + o[d][r];
        cat_out[(size_t)qrow * CATK + head * HD + d * 16 + l16] = (__bf16)(v * inv_den[r]);
      }
    }
  }
}

// ---------------- launch ----------------
extern "C" void kernel_launch(void* const* d_in, const int* in_sizes, int n_in,
                              void* d_out, int out_size, void* d_ws, size_t ws_size,
                              hipStream_t stream)
{
  const float* x   = (const float*)d_in[0];
  const float* con = (const float*)d_in[1];
  const float* vec = (const float*)d_in[2];
  const float* pe  = (const float*)d_in[3];
  const float* cpe = (const float*)d_in[4];
  const float* w1  = (const float*)d_in[5];
  const float* b1  = (const float*)d_in[6];
  const float* w2  = (const float*)d_in[7];
  const float* b2  = (const float*)d_in[8];
  const float* qsc = (const float*)d_in[9];
  const float* ksc = (const float*)d_in[10];
  const float* mw  = (const float*)d_in[11];
  const float* mb  = (const float*)d_in[12];
  float* out = (float*)d_out;

  char* ws = (char*)d_ws;
  float*  mvec = (float*)(ws + OFF_MVEC);
  __bf16* w1b  = (__bf16*)(ws + OFF_W1B);
  __bf16* w2b  = (__bf16*)(ws + OFF_W2B);
  __bf16* xm1  = (__bf16*)(ws + OFF_XM1);
  __bf16* qh1  = (__bf16*)(ws + OFF_QH1);
  __bf16* qkv1 = (__bf16*)(ws + OFF_QKV1);
  __bf16* kh1  = (__bf16*)(ws + OFF_KH1);
  __bf16* vh1  = (__bf16*)(ws + OFF_VH1);
  __bf16* cat1 = (__bf16*)(ws + OFF_CAT1);
  __bf16* xm2  = (__bf16*)(ws + OFF_XM2);
  __bf16* qkv2 = (__bf16*)(ws + OFF_QKV2);
  __bf16* vh2s = (__bf16*)(ws + OFF_VH2S);
  __bf16* qh2  = (__bf16*)(ws + OFF_QH2);
  __bf16* kh2  = (__bf16*)(ws + OFF_KH2);
  __bf16* cat2 = (__bf16*)(ws + OFF_CAT2);

  // weights -> bf16
  f2b_kernel<<<16128, 256, 0, stream>>>(w1, w1b, (NQKV * HID) / 4);
  f2b_kernel<<<11520, 256, 0, stream>>>(w2, w2b, (HID * CATK) / 4);
  // modulation vector
  mod_kernel<<<1152, 256, 0, stream>>>(vec, mw, mb, mvec);

  // ---- block 1 ----
  ln_mod_kernel<<<LX, 256, 0, stream>>>(x, mvec, xm1);
  gemm256<0><<<dim3(NQKV / 256, LX / 256), 512, 0, stream>>>(
      xm1, w1b, LX, HID, b1, qkv1, cat1, vh1, LX, nullptr, nullptr, nullptr);
  qk_prep<<<(LX * NHEAD) / 4, 256, 0, stream>>>(
      qkv1, LX, qkv1, 0, LX, LX, pe, qsc, ksc, qh1, LX, kh1, LX);
  attn_kernel<0><<<NHEAD * (LX / 64), 512, 0, stream>>>(
      qh1, kh1, vh1, LX, vh1, LX, 0, 0, LX, LX, LX, LX, LX / 64, cat1);
  gemm256<1><<<dim3(HID / 256, LX / 256), 512, 0, stream>>>(
      cat1, w2b, LX, CATK, b2, nullptr, nullptr, nullptr, 0, x, mvec + 3072, out);

  // ---- block 2 (only 20 concept queries matter; k/v of image rows reused from block 1) ----
  ln_mod_kernel<<<NCON, 256, 0, stream>>>(con, mvec, xm2);
  gemm_bt<0><<<dim3(NQKV / 128, 1), 256, 0, stream>>>(
      xm2, w1b, NCON, HID, b1, qkv2, cat2, vh2s, 32, nullptr, nullptr, nullptr);
  qk_prep<<<(LC2 * NHEAD + 3) / 4, 256, 0, stream>>>(
      qkv2, NCON, qkv1, 236, LC2, NCON, cpe, qsc, ksc, qh2, 64, kh2, LC2);
  attn_kernel<1><<<NHEAD, 512, 0, stream>>>(
      qh2, kh2, vh2s, 32, vh1, LX, 236, NCON, NCON, LC2, 64, LC2, 1, cat2);
  gemm_bt<1><<<dim3(HID / 128, 1), 256, 0, stream>>>(
      cat2, w2b, NCON, CATK, b2, nullptr, nullptr, nullptr, 0, con, mvec + 3072,
      out + (size_t)LX * HID);
}

// Round 4
// 1243.531 us; speedup vs baseline: 1.1651x; 1.0607x over previous
//
#include <hip/hip_runtime.h>
#include <cstdint>
#include <cstddef>

typedef float        f32x4  __attribute__((ext_vector_type(4)));
typedef __bf16       bf16x8 __attribute__((ext_vector_type(8)));
typedef unsigned int u32x4  __attribute__((ext_vector_type(4)));
typedef unsigned int u32x2  __attribute__((ext_vector_type(2)));

// ---------------- problem dims ----------------
static constexpr int HID   = 1536;
static constexpr int NHEAD = 12;
static constexpr int HD    = 128;
static constexpr int NQKV  = 10752;   // 3*HID + 4*HID
static constexpr int CATK  = 7680;    // HID + 4*HID
static constexpr int LX    = 4352;    // text 256 + 4096 image
static constexpr int LC2   = 4116;    // 20 concepts + 4096 image
static constexpr int NCON  = 20;

// q pre-scale: 1/sqrt(128) * log2(e)  (softmax computed in exp2 domain)
static constexpr float QSCL = 0.08838834764831845f * 1.4426950408889634f;
// fixed softmax shift (rmsnorm bounds |S_exp2| <= 16.34 << 24)
static constexpr float SHIFT = 24.0f;

// ---------------- workspace layout (bytes) ----------------
static constexpr size_t OFF_MVEC = 0;                          // 4608 f32
static constexpr size_t OFF_W1B  = 18432;                      // 10752x1536 bf16
static constexpr size_t OFF_W2B  = OFF_W1B  + 33030144ull;     // 1536x7680 bf16
static constexpr size_t OFF_XM1  = OFF_W2B  + 23592960ull;     // 4352x1536 bf16 (later aliased by qh1)
static constexpr size_t OFF_QH1  = OFF_XM1;                    // [12][4352][128] bf16
static constexpr size_t OFF_QKV1 = OFF_XM1  + 13369344ull;     // 4352x3072 bf16 (q,k raw)
static constexpr size_t OFF_KH1  = OFF_QKV1 + 26738688ull;     // [12][4352][128]
static constexpr size_t OFF_VH1  = OFF_KH1  + 13369344ull;     // [12][128][4352] (transposed)
static constexpr size_t OFF_CAT1 = OFF_VH1  + 13369344ull;     // 4352x7680 bf16
// block-2 scratch aliased inside cat1 (cat1 dead after GEMM2 of block 1):
static constexpr size_t OFF_XM2  = OFF_CAT1;                   // 64x1536 bf16
static constexpr size_t OFF_QKV2 = OFF_XM2  + 196608ull;       // 32x3072 bf16
static constexpr size_t OFF_VH2S = OFF_QKV2 + 196608ull;       // [12][128][32]
static constexpr size_t OFF_QH2  = OFF_VH2S + 98304ull;        // [12][64][128]
static constexpr size_t OFF_KH2  = OFF_QH2  + 196608ull;       // [12][4116][128]
static constexpr size_t OFF_CAT2 = OFF_KH2  + 12644352ull;     // 32x7680 bf16
// total required: OFF_CAT1 + 66846720 = 190,334,976 bytes

// async global->LDS, 16B per lane. LDS dest must be wave-uniform base; HW
// writes base + lane*16 (m104). Global src is per-lane.
__device__ __forceinline__ void gload_lds16(const void* g, void* l)
{
  __builtin_amdgcn_global_load_lds(
      (const __attribute__((address_space(1))) unsigned int*)g,
      (__attribute__((address_space(3))) unsigned int*)l, 16, 0, 0);
}

// raw phase barrier: NO waitcnt drain (compiler inserts exact lgkmcnt before
// the first dependent MFMA after the barrier; counted vmcnt survives).
#define PHASE_BAR() asm volatile("s_barrier" ::: "memory")

// ---------------- small kernels ----------------

__global__ __launch_bounds__(256) void f2b_kernel(const float* __restrict__ in,
                                                  __bf16* __restrict__ out, int n4)
{
  int i = blockIdx.x * 256 + threadIdx.x;
  if (i >= n4) return;
  f32x4 v = *((const f32x4*)in + i);
  union { __bf16 h[4]; u32x2 u; } cv;
  cv.h[0] = (__bf16)v[0]; cv.h[1] = (__bf16)v[1];
  cv.h[2] = (__bf16)v[2]; cv.h[3] = (__bf16)v[3];
  *((u32x2*)out + i) = cv.u;
}

// m = silu(vec) @ mod_w.T + mod_b   (one wave per output)
__global__ __launch_bounds__(256) void mod_kernel(const float* __restrict__ vec,
                                                  const float* __restrict__ mod_w,
                                                  const float* __restrict__ mod_b,
                                                  float* __restrict__ m)
{
  int o = blockIdx.x * 4 + (threadIdx.x >> 6);
  int lane = threadIdx.x & 63;
  float s = 0.0f;
  for (int k = lane; k < HID; k += 64) {
    float v = vec[k];
    float sv = v / (1.0f + expf(-v));
    s += sv * mod_w[(size_t)o * HID + k];
  }
  #pragma unroll
  for (int msk = 32; msk; msk >>= 1) s += __shfl_xor(s, msk);
  if (lane == 0) m[o] = s + mod_b[o];
}

__device__ __forceinline__ float block_sum256(float v, float* red)
{
  #pragma unroll
  for (int msk = 32; msk; msk >>= 1) v += __shfl_xor(v, msk);
  int w = threadIdx.x >> 6;
  if ((threadIdx.x & 63) == 0) red[w] = v;
  __syncthreads();
  float s = red[0] + red[1] + red[2] + red[3];
  __syncthreads();
  return s;
}

// xm = (1+scale)*layernorm(x) + shift, bf16 out. one block per row.
// Optional prefill of the split-K GEMM2 output: outp = x + gate*b2
// (the affine part of the residual epilogue; split-K blocks atomicAdd the rest).
__global__ __launch_bounds__(256) void ln_mod_kernel(const float* __restrict__ x,
                                                     const float* __restrict__ mvec,
                                                     __bf16* __restrict__ out,
                                                     const float* __restrict__ b2,
                                                     float* __restrict__ outp)
{
  __shared__ float red[4];
  size_t row = blockIdx.x;
  const float* xr = x + row * HID;
  float v[6]; float s = 0.0f;
  #pragma unroll
  for (int i = 0; i < 6; i++) { v[i] = xr[threadIdx.x + i * 256]; s += v[i]; }
  float mu = block_sum256(s, red) * (1.0f / HID);
  float s2 = 0.0f;
  #pragma unroll
  for (int i = 0; i < 6; i++) { float d = v[i] - mu; s2 += d * d; }
  float var = block_sum256(s2, red) * (1.0f / HID);
  float rinv = rsqrtf(var + 1e-6f);
  #pragma unroll
  for (int i = 0; i < 6; i++) {
    int h = threadIdx.x + i * 256;
    float xm = (v[i] - mu) * rinv;
    xm = (1.0f + mvec[HID + h]) * xm + mvec[h];
    out[row * HID + h] = (__bf16)xm;
    if (outp) outp[row * HID + h] = v[i] + mvec[3072 + h] * b2[h];
  }
}

// ---------------- 256x256 8-phase GEMM (B^T layout): C[m,n]=sum_k A[m,k]B[n,k]
// 512 threads = 8 waves (2M x 4N), per-wave output 128x64, BK=64.
// LDS 128 KiB: As/Bs[2][256][64] double-buffered.
// T2 swizzle (full 3-bit spread): LDS[row][slot] holds global slot
//   slot ^ (row&7) (slots = 8-element/16B units). gload_lds dest stays
//   linear; the global SOURCE is pre-permuted with the same involution;
//   ds_reads XOR their slot with row&7. Conflict-free b128 (2 lanes/slot).
// T3/T4: 4 phases/K-tile, raw s_barrier boundaries; counted vmcnt(8) once
//   per tile (S(t+1) landed, S(t+2) in flight); vmcnt(0) only at drain.
// T5: setprio(1) around each 16-MFMA cluster.
// MODE 0: qkv/v-transpose/gelu-cat scatter.  MODE 1: residual+gate store.
// MODE 2: split-K partial — atomicAdd(out, gate*acc); K = per-split length,
//   lda = full row stride, blockIdx.z = split index (bias folded in prefill).
template<int MODE>
__global__ __launch_bounds__(512, 2) void gemm256(const __bf16* __restrict__ A,
                                                  const __bf16* __restrict__ B,
                                                  int M, int K, int lda,
                                                  const float* __restrict__ bias,
                                                  __bf16* __restrict__ qkv_out,
                                                  __bf16* __restrict__ cat_out,
                                                  __bf16* __restrict__ vh_out, int vkeys,
                                                  const float* __restrict__ res,
                                                  const float* __restrict__ gate,
                                                  float* __restrict__ out)
{
  const int tid = threadIdx.x;
  const int lane = tid & 63, wave = tid >> 6;
  const int quad = lane >> 4, l16 = lane & 15;
  const int wmh = wave >> 2;            // M half (0/1) -> rows wmh*128..+127
  const int wnq = wave & 3;             // N quarter    -> cols wnq*64..+63
  const int m0 = blockIdx.y * 256, n0 = blockIdx.x * 256;
  const int kstart = blockIdx.z * K;
  const int rsw = l16 & 7;              // read-side slot XOR (row&7)

  __shared__ __bf16 As[2][256][64];
  __shared__ __bf16 Bs[2][256][64];

  const f32x4 fzero = {0.0f, 0.0f, 0.0f, 0.0f};
  f32x4 acc[8][4];
  #pragma unroll
  for (int i = 0; i < 8; i++)
    #pragma unroll
    for (int j = 0; j < 4; j++) acc[i][j] = fzero;

  // staging: wave w owns A/B rows [w*32,+32); 4 issues each (8 rows x 128B).
  // lane -> LDS (row=l>>3, slot=l&7); source slot = (l&7) ^ (l>>3) so that
  // LDS[row][slot] = global[row][slot ^ (row&7)].
  const int srow = lane >> 3;
  const int scol = ((lane & 7) ^ srow) * 8;
  const __bf16* Ag = A + (size_t)(m0 + wave * 32 + srow) * lda + kstart + scol;
  const __bf16* Bg = B + (size_t)(n0 + wave * 32 + srow) * lda + kstart + scol;

  auto stageA = [&](int buf, int k) {
    #pragma unroll
    for (int j = 0; j < 4; j++)
      gload_lds16(Ag + (size_t)(j * 8) * lda + k, &As[buf][wave * 32 + j * 8][0]);
  };
  auto stageB = [&](int buf, int k) {
    #pragma unroll
    for (int j = 0; j < 4; j++)
      gload_lds16(Bg + (size_t)(j * 8) * lda + k, &Bs[buf][wave * 32 + j * 8][0]);
  };

  const int NT = K >> 6;
  // prologue: tiles 0 and 1. S(0)=first 8 issues, S(1)=next 8.
  stageB(0, 0);  stageA(0, 0);
  stageB(1, 64); stageA(1, 64);
  asm volatile("s_waitcnt vmcnt(8)" ::: "memory");   // own S(0) landed
  PHASE_BAR();                                       // => everyone's S(0) landed

  for (int t = 0; t < NT; ++t) {
    const int b = t & 1;
    const int kn = (t + 2) << 6;
    bf16x8 aM[4][2], bN0[2][2], bN1[2][2];

    // ---- phase 0: quadrant (M0,N0); 12 ds_reads ----
    #pragma unroll
    for (int f = 0; f < 4; f++)
      #pragma unroll
      for (int kk = 0; kk < 2; kk++)
        aM[f][kk] = *(const bf16x8*)&As[b][wmh * 128 + f * 16 + l16][((kk * 4 + quad) ^ rsw) * 8];
    #pragma unroll
    for (int g = 0; g < 2; g++)
      #pragma unroll
      for (int kk = 0; kk < 2; kk++)
        bN0[g][kk] = *(const bf16x8*)&Bs[b][wnq * 64 + g * 16 + l16][((kk * 4 + quad) ^ rsw) * 8];
    PHASE_BAR();
    __builtin_amdgcn_s_setprio(1);
    #pragma unroll
    for (int f = 0; f < 4; f++)
      #pragma unroll
      for (int g = 0; g < 2; g++)
        #pragma unroll
        for (int kk = 0; kk < 2; kk++)
          acc[f][g] = __builtin_amdgcn_mfma_f32_16x16x32_bf16(aM[f][kk], bN0[g][kk], acc[f][g], 0, 0, 0);
    __builtin_amdgcn_s_setprio(0);
    PHASE_BAR();

    // ---- phase 1: (M0,N1); 4 ds_reads ----
    #pragma unroll
    for (int g = 0; g < 2; g++)
      #pragma unroll
      for (int kk = 0; kk < 2; kk++)
        bN1[g][kk] = *(const bf16x8*)&Bs[b][wnq * 64 + 32 + g * 16 + l16][((kk * 4 + quad) ^ rsw) * 8];
    PHASE_BAR();
    __builtin_amdgcn_s_setprio(1);
    #pragma unroll
    for (int f = 0; f < 4; f++)
      #pragma unroll
      for (int g = 0; g < 2; g++)
        #pragma unroll
        for (int kk = 0; kk < 2; kk++)
          acc[f][2 + g] = __builtin_amdgcn_mfma_f32_16x16x32_bf16(aM[f][kk], bN1[g][kk], acc[f][2 + g], 0, 0, 0);
    __builtin_amdgcn_s_setprio(0);
    PHASE_BAR();

    // ---- phase 2: (M1,N1); 8 ds_reads; stage B(t+2) (B region dead) ----
    #pragma unroll
    for (int f = 0; f < 4; f++)
      #pragma unroll
      for (int kk = 0; kk < 2; kk++)
        aM[f][kk] = *(const bf16x8*)&As[b][wmh * 128 + 64 + f * 16 + l16][((kk * 4 + quad) ^ rsw) * 8];
    if (t + 2 < NT) stageB(b, kn);
    PHASE_BAR();
    __builtin_amdgcn_s_setprio(1);
    #pragma unroll
    for (int f = 0; f < 4; f++)
      #pragma unroll
      for (int g = 0; g < 2; g++)
        #pragma unroll
        for (int kk = 0; kk < 2; kk++)
          acc[4 + f][2 + g] = __builtin_amdgcn_mfma_f32_16x16x32_bf16(aM[f][kk], bN1[g][kk], acc[4 + f][2 + g], 0, 0, 0);
    __builtin_amdgcn_s_setprio(0);
    PHASE_BAR();

    // ---- phase 3: (M1,N0); stage A(t+2) (A region dead); tile-boundary vmcnt ----
    if (t + 2 < NT) stageA(b, kn);
    PHASE_BAR();
    __builtin_amdgcn_s_setprio(1);
    #pragma unroll
    for (int f = 0; f < 4; f++)
      #pragma unroll
      for (int g = 0; g < 2; g++)
        #pragma unroll
        for (int kk = 0; kk < 2; kk++)
          acc[4 + f][g] = __builtin_amdgcn_mfma_f32_16x16x32_bf16(aM[f][kk], bN0[g][kk], acc[4 + f][g], 0, 0, 0);
    __builtin_amdgcn_s_setprio(0);
    if (t + 1 < NT) {
      if (t + 2 < NT) asm volatile("s_waitcnt vmcnt(8)" ::: "memory");  // S(t+1) landed, S(t+2) in flight
      else            asm volatile("s_waitcnt vmcnt(0)" ::: "memory");  // final drain
    }
    PHASE_BAR();
  }

  // ---- epilogue ----
  #pragma unroll
  for (int mf = 0; mf < 8; mf++) {
    #pragma unroll
    for (int r = 0; r < 4; r++) {
      int gm = m0 + wmh * 128 + mf * 16 + quad * 4 + r;
      if (gm >= M) continue;
      #pragma unroll
      for (int nf = 0; nf < 4; nf++) {
        int gn = n0 + wnq * 64 + nf * 16 + l16;
        if constexpr (MODE == 0) {
          float v = acc[mf][nf][r] + bias[gn];
          if (gn < 3072) {                 // q,k raw
            qkv_out[(size_t)gm * 3072 + gn] = (__bf16)v;
          } else if (gn < 4608) {          // v -> transposed [head*128+d][key]
            vh_out[(size_t)(gn - 3072) * vkeys + gm] = (__bf16)v;
          } else {                         // mlp -> gelu -> cat cols [1536,7680)
            float g = 0.5f * v * (1.0f + tanhf(0.7978845608028654f * (v + 0.044715f * v * v * v)));
            cat_out[(size_t)gm * CATK + (gn - 3072)] = (__bf16)g;
          }
        } else if constexpr (MODE == 1) {
          float v = acc[mf][nf][r] + bias[gn];
          out[(size_t)gm * HID + gn] = res[(size_t)gm * HID + gn] + gate[gn] * v;
        } else {                           // split-K partial
          unsafeAtomicAdd(&out[(size_t)gm * HID + gn], gate[gn] * acc[mf][nf][r]);
        }
      }
    }
  }
}

// ---------------- legacy 128x128 GEMM (block-2 small dispatches, M=20) ----
template<int MODE>
__global__ __launch_bounds__(256) void gemm_bt(const __bf16* __restrict__ A,
                                               const __bf16* __restrict__ B,
                                               int M, int K,
                                               const float* __restrict__ bias,
                                               __bf16* __restrict__ qkv_out,
                                               __bf16* __restrict__ cat_out,
                                               __bf16* __restrict__ vh_out, int vkeys,
                                               const float* __restrict__ res,
                                               const float* __restrict__ gate,
                                               float* __restrict__ out)
{
  const int tid = threadIdx.x;
  const int lane = tid & 63, wave = tid >> 6;
  const int quad = lane >> 4, l16 = lane & 15;
  const int m0 = blockIdx.y * 128, n0 = blockIdx.x * 128;
  const int wm = (wave & 1) * 64, wn = (wave >> 1) * 64;
  const int rsw = l16 & 7;

  __shared__ __bf16 As[128][64];
  __shared__ __bf16 Bs[128][64];

  const f32x4 fzero = {0.0f, 0.0f, 0.0f, 0.0f};
  f32x4 acc[4][4];
  #pragma unroll
  for (int i = 0; i < 4; i++)
    #pragma unroll
    for (int j = 0; j < 4; j++) acc[i][j] = fzero;

  const int srow = lane >> 3;
  const int scol = ((lane & 7) ^ srow) * 8;   // same involution as gemm256
  const int rbase = wave * 32 + srow;
  const __bf16* Ab = A + (size_t)(m0 + rbase) * K + scol;
  const __bf16* Bb = B + (size_t)(n0 + rbase) * K + scol;

  for (int k0 = 0; k0 < K; k0 += 64) {
    __syncthreads();
    #pragma unroll
    for (int j = 0; j < 4; j++) {
      gload_lds16(Ab + (size_t)(j * 8) * K + k0, &As[wave * 32 + j * 8][0]);
      gload_lds16(Bb + (size_t)(j * 8) * K + k0, &Bs[wave * 32 + j * 8][0]);
    }
    __syncthreads();
    #pragma unroll
    for (int kk = 0; kk < 2; kk++) {
      bf16x8 af[4], bfr[4];
      #pragma unroll
      for (int i = 0; i < 4; i++) af[i]  = *(const bf16x8*)&As[wm + i * 16 + l16][((kk * 4 + quad) ^ rsw) * 8];
      #pragma unroll
      for (int j = 0; j < 4; j++) bfr[j] = *(const bf16x8*)&Bs[wn + j * 16 + l16][((kk * 4 + quad) ^ rsw) * 8];
      #pragma unroll
      for (int i = 0; i < 4; i++)
        #pragma unroll
        for (int j = 0; j < 4; j++)
          acc[i][j] = __builtin_amdgcn_mfma_f32_16x16x32_bf16(af[i], bfr[j], acc[i][j], 0, 0, 0);
    }
  }

  #pragma unroll
  for (int i = 0; i < 4; i++) {
    #pragma unroll
    for (int r = 0; r < 4; r++) {
      int gm = m0 + wm + i * 16 + quad * 4 + r;
      if (gm >= M) continue;
      #pragma unroll
      for (int j = 0; j < 4; j++) {
        int gn = n0 + wn + j * 16 + l16;
        float v = acc[i][j][r] + bias[gn];
        if constexpr (MODE == 0) {
          if (gn < 3072) {
            qkv_out[(size_t)gm * 3072 + gn] = (__bf16)v;
          } else if (gn < 4608) {
            vh_out[(size_t)(gn - 3072) * vkeys + gm] = (__bf16)v;
          } else {
            float g = 0.5f * v * (1.0f + tanhf(0.7978845608028654f * (v + 0.044715f * v * v * v)));
            cat_out[(size_t)gm * CATK + (gn - 3072)] = (__bf16)g;
          }
        } else {
          out[(size_t)gm * HID + gn] = res[(size_t)gm * HID + gn] + gate[gn] * v;
        }
      }
    }
  }
}

// ---------------- q/k rmsnorm + rope preprocessing ----------------
__global__ __launch_bounds__(256) void qk_prep(const __bf16* __restrict__ src0, int rows0,
                                               const __bf16* __restrict__ src1, int off1,
                                               int total_rows, int q_rows,
                                               const float* __restrict__ pe,
                                               const float* __restrict__ qscale,
                                               const float* __restrict__ kscale,
                                               __bf16* __restrict__ qh, int q_stride,
                                               __bf16* __restrict__ kh, int k_stride)
{
  int wid = blockIdx.x * 4 + (threadIdx.x >> 6);
  int lane = threadIdx.x & 63;
  int r = wid / NHEAD, h = wid - (wid / NHEAD) * NHEAD;
  if (r >= total_rows) return;
  const __bf16* src = (r < rows0) ? (src0 + (size_t)r * 3072)
                                  : (src1 + (size_t)(r + off1) * 3072);
  const float* pep = pe + ((size_t)r * 64 + lane) * 4;
  float e00 = pep[0], e01 = pep[1], e10 = pep[2], e11 = pep[3];

  { // k
    const __bf16* p = src + HID + h * HD + 2 * lane;
    float a = (float)p[0], b = (float)p[1];
    float ss = a * a + b * b;
    #pragma unroll
    for (int msk = 32; msk; msk >>= 1) ss += __shfl_xor(ss, msk);
    float rinv = rsqrtf(ss * (1.0f / HD) + 1e-6f);
    a *= rinv * kscale[2 * lane]; b *= rinv * kscale[2 * lane + 1];
    float ra = e00 * a + e01 * b, rb = e10 * a + e11 * b;
    __bf16* o = kh + ((size_t)h * k_stride + r) * HD + 2 * lane;
    o[0] = (__bf16)ra; o[1] = (__bf16)rb;
  }
  if (r < q_rows) { // q (with folded softmax scale, exp2 domain)
    const __bf16* p = src + h * HD + 2 * lane;
    float a = (float)p[0], b = (float)p[1];
    float ss = a * a + b * b;
    #pragma unroll
    for (int msk = 32; msk; msk >>= 1) ss += __shfl_xor(ss, msk);
    float rinv = rsqrtf(ss * (1.0f / HD) + 1e-6f);
    a *= rinv * qscale[2 * lane]; b *= rinv * qscale[2 * lane + 1];
    float ra = (e00 * a + e01 * b) * QSCL, rb = (e10 * a + e11 * b) * QSCL;
    __bf16* o = qh + ((size_t)h * q_stride + r) * HD + 2 * lane;
    o[0] = (__bf16)ra; o[1] = (__bf16)rb;
  }
}

// ---------------- flash attention, fixed-shift softmax ----------------
template<int GEN>
__global__ __launch_bounds__(512, 4) void attn_kernel(const __bf16* __restrict__ qh,
                                                      const __bf16* __restrict__ kh,
                                                      const __bf16* __restrict__ vA, int vA_stride,
                                                      const __bf16* __restrict__ vB, int vB_stride,
                                                      int v_boff, int v_split,
                                                      int Lq, int Lk, int q_stride, int k_stride,
                                                      int nqt,
                                                      __bf16* __restrict__ cat_out)
{
  const int tid = threadIdx.x, lane = tid & 63, wave = tid >> 6;
  const int quad = lane >> 4, l16 = lane & 15;
  const int qsub = wave >> 1, kg = wave & 1;

  int bid = blockIdx.x;
  if constexpr (GEN == 0) {
    int nb = gridDim.x;
    if ((nb & 7) == 0) {
      int per = nb >> 3;
      bid = (bid & 7) * per + (bid >> 3);
    }
  }
  const int head = bid / nqt, qt = bid - head * nqt;
  const int q0 = qt * 64 + qsub * 16;

  __shared__ __align__(16) unsigned char lds_raw[46080];
  __bf16 (*Ks)[136]     = (__bf16(*)[136])(lds_raw);            // [64][136]
  __bf16 (*Vt)[72]      = (__bf16(*)[72])(lds_raw + 17408);     // [128][72]
  __bf16 (*Ps)[16][40]  = (__bf16(*)[16][40])(lds_raw + 35840); // [8][16][40]
  float*  Of            = (float*)lds_raw;                      // merge alias [64][132]
  float*  Lf            = (float*)(lds_raw + 35840);            // merge alias [8][16]

  const f32x4 fzero = {0.0f, 0.0f, 0.0f, 0.0f};
  const u32x4 uzero = {0, 0, 0, 0};

  bf16x8 ones;
  #pragma unroll
  for (int e = 0; e < 8; e++) ones[e] = (__bf16)1.0f;

  bf16x8 qf[4];
  {
    int qrow = q0 + l16;
    if (GEN == 0 || qrow < Lq) {
      const __bf16* qp = qh + ((size_t)head * q_stride + qrow) * HD + quad * 8;
      #pragma unroll
      for (int c = 0; c < 4; c++) qf[c] = *(const bf16x8*)(qp + c * 32);
    } else {
      #pragma unroll
      for (int c = 0; c < 4; c++) qf[c] = __builtin_bit_cast(bf16x8, uzero);
    }
  }
  f32x4 o[8];
  #pragma unroll
  for (int d = 0; d < 8; d++) o[d] = fzero;
  f32x4 l_acc = fzero;

  const int krowA = tid >> 4, kcolA = (tid & 15) * 8;
  const int vdimA = tid >> 3, vkcA  = tid & 7;

  const __bf16* khb = kh + (size_t)head * k_stride * HD;
  const __bf16* vaB = vA + (size_t)head * HD * vA_stride;
  const __bf16* vbB = vB + (size_t)head * HD * vB_stride + v_boff;

  auto vload = [&](int dim, int kb) -> u32x4 {
    if constexpr (GEN == 0) {
      return *(const u32x4*)(vbB + (size_t)dim * vB_stride + kb);
    } else {
      u32x4 vd = uzero;
      if (kb < Lk) {
        if (kb + 8 <= v_split) {
          vd = *(const u32x4*)(vaB + (size_t)dim * vA_stride + kb);
        } else if (kb >= v_split && kb + 8 <= Lk) {
          vd = *(const u32x4*)(vbB + (size_t)dim * vB_stride + kb);
        } else {
          __bf16* ve = (__bf16*)&vd;
          #pragma unroll
          for (int e = 0; e < 8; e++) {
            int key = kb + e;
            if (key < Lk)
              ve[e] = (key < v_split) ? vaB[(size_t)dim * vA_stride + key]
                                      : vbB[(size_t)dim * vB_stride + key];
          }
        }
      }
      return vd;
    }
  };
  auto kload = [&](int kr, int col) -> u32x4 {
    if constexpr (GEN == 0) {
      return *(const u32x4*)(khb + (size_t)kr * HD + col);
    } else {
      return (kr < Lk) ? *(const u32x4*)(khb + (size_t)kr * HD + col) : uzero;
    }
  };

  u32x4 pk0, pk1, pv0, pv1;
  pk0 = kload(krowA, kcolA);
  pk1 = kload(krowA + 32, kcolA);
  pv0 = vload(vdimA, vkcA * 8);
  pv1 = vload(vdimA + 64, vkcA * 8);

  const int nkt = (Lk + 63) >> 6;
  for (int t = 0; t < nkt; ++t) {
    const int kt0 = t * 64;
    __syncthreads();
    *(u32x4*)&Ks[krowA][kcolA]      = pk0;
    *(u32x4*)&Ks[krowA + 32][kcolA] = pk1;
    *(u32x4*)&Vt[vdimA][vkcA * 8]      = pv0;
    *(u32x4*)&Vt[vdimA + 64][vkcA * 8] = pv1;
    if (t + 1 < nkt) {
      const int nt0 = kt0 + 64;
      pk0 = kload(nt0 + krowA, kcolA);
      pk1 = kload(nt0 + krowA + 32, kcolA);
      pv0 = vload(vdimA, nt0 + vkcA * 8);
      pv1 = vload(vdimA + 64, nt0 + vkcA * 8);
    }
    __syncthreads();

    f32x4 s[2];
    __builtin_amdgcn_s_setprio(1);
    #pragma unroll
    for (int nt = 0; nt < 2; nt++) {
      s[nt] = fzero;
      #pragma unroll
      for (int c = 0; c < 4; c++) {
        bf16x8 b = *(const bf16x8*)&Ks[kg * 32 + nt * 16 + l16][c * 32 + quad * 8];
        s[nt] = __builtin_amdgcn_mfma_f32_16x16x32_bf16(qf[c], b, s[nt], 0, 0, 0);
      }
      if constexpr (GEN != 0) {
        int kidx = kt0 + kg * 32 + nt * 16 + l16;
        if (kidx >= Lk) { s[nt][0] = -1e30f; s[nt][1] = -1e30f; s[nt][2] = -1e30f; s[nt][3] = -1e30f; }
      }
    }
    __builtin_amdgcn_s_setprio(0);

    // fixed-shift P (no max tracking, no rescale)
    #pragma unroll
    for (int r = 0; r < 4; r++) {
      int prow = quad * 4 + r;
      Ps[wave][prow][l16]      = (__bf16)exp2f(s[0][r] - SHIFT);
      Ps[wave][prow][16 + l16] = (__bf16)exp2f(s[1][r] - SHIFT);
    }
    // no barrier: Ps is wave-local (intra-wave DS ordering + compiler lgkmcnt)

    bf16x8 pf = *(const bf16x8*)&Ps[wave][l16][quad * 8];
    __builtin_amdgcn_s_setprio(1);
    l_acc = __builtin_amdgcn_mfma_f32_16x16x32_bf16(pf, ones, l_acc, 0, 0, 0);
    #pragma unroll
    for (int dt = 0; dt < 8; dt++) {
      bf16x8 bv = *(const bf16x8*)&Vt[dt * 16 + l16][kg * 32 + quad * 8];
      o[dt] = __builtin_amdgcn_mfma_f32_16x16x32_bf16(pf, bv, o[dt], 0, 0, 0);
    }
    __builtin_amdgcn_s_setprio(0);
  }

  // ---- merge the two kg halves: plain sums ----
  __syncthreads();                         // all tiles done; LDS reusable
  if (l16 == 0) {
    #pragma unroll
    for (int r = 0; r < 4; r++) Lf[wave * 16 + quad * 4 + r] = l_acc[r];
  }
  __syncthreads();
  float inv_den[4];
  #pragma unroll
  for (int r = 0; r < 4; r++)
    inv_den[r] = 1.0f / (l_acc[r] + Lf[(wave ^ 1) * 16 + quad * 4 + r]);
  if (kg == 0) {
    #pragma unroll
    for (int d = 0; d < 8; d++)
      #pragma unroll
      for (int r = 0; r < 4; r++)
        Of[(size_t)(qsub * 16 + quad * 4 + r) * 132 + d * 16 + l16] = o[d][r];
  }
  __syncthreads();
  if (kg == 1) {
    #pragma unroll
    for (int r = 0; r < 4; r++) {
      int qrow = q0 + quad * 4 + r;
      if (qrow >= Lq) continue;
      #pragma unroll
      for (int d = 0; d < 8; d++) {
        float v = Of[(size_t)(qsub * 16 + quad * 4 + r) * 132 + d * 16 + l16] + o[d][r];
        cat_out[(size_t)qrow * CATK + head * HD + d * 16 + l16] = (__bf16)(v * inv_den[r]);
      }
    }
  }
}

// ---------------- launch ----------------
extern "C" void kernel_launch(void* const* d_in, const int* in_sizes, int n_in,
                              void* d_out, int out_size, void* d_ws, size_t ws_size,
                              hipStream_t stream)
{
  const float* x   = (const float*)d_in[0];
  const float* con = (const float*)d_in[1];
  const float* vec = (const float*)d_in[2];
  const float* pe  = (const float*)d_in[3];
  const float* cpe = (const float*)d_in[4];
  const float* w1  = (const float*)d_in[5];
  const float* b1  = (const float*)d_in[6];
  const float* w2  = (const float*)d_in[7];
  const float* b2  = (const float*)d_in[8];
  const float* qsc = (const float*)d_in[9];
  const float* ksc = (const float*)d_in[10];
  const float* mw  = (const float*)d_in[11];
  const float* mb  = (const float*)d_in[12];
  float* out = (float*)d_out;

  char* ws = (char*)d_ws;
  float*  mvec = (float*)(ws + OFF_MVEC);
  __bf16* w1b  = (__bf16*)(ws + OFF_W1B);
  __bf16* w2b  = (__bf16*)(ws + OFF_W2B);
  __bf16* xm1  = (__bf16*)(ws + OFF_XM1);
  __bf16* qh1  = (__bf16*)(ws + OFF_QH1);
  __bf16* qkv1 = (__bf16*)(ws + OFF_QKV1);
  __bf16* kh1  = (__bf16*)(ws + OFF_KH1);
  __bf16* vh1  = (__bf16*)(ws + OFF_VH1);
  __bf16* cat1 = (__bf16*)(ws + OFF_CAT1);
  __bf16* xm2  = (__bf16*)(ws + OFF_XM2);
  __bf16* qkv2 = (__bf16*)(ws + OFF_QKV2);
  __bf16* vh2s = (__bf16*)(ws + OFF_VH2S);
  __bf16* qh2  = (__bf16*)(ws + OFF_QH2);
  __bf16* kh2  = (__bf16*)(ws + OFF_KH2);
  __bf16* cat2 = (__bf16*)(ws + OFF_CAT2);

  // weights -> bf16
  f2b_kernel<<<16128, 256, 0, stream>>>(w1, w1b, (NQKV * HID) / 4);
  f2b_kernel<<<11520, 256, 0, stream>>>(w2, w2b, (HID * CATK) / 4);
  // modulation vector
  mod_kernel<<<1152, 256, 0, stream>>>(vec, mw, mb, mvec);

  // ---- block 1 ----
  // ln_mod also prefills out = x + gate*b2 (affine part of split-K GEMM2)
  ln_mod_kernel<<<LX, 256, 0, stream>>>(x, mvec, xm1, b2, out);
  gemm256<0><<<dim3(NQKV / 256, LX / 256), 512, 0, stream>>>(
      xm1, w1b, LX, HID, HID, b1, qkv1, cat1, vh1, LX, nullptr, nullptr, nullptr);
  qk_prep<<<(LX * NHEAD) / 4, 256, 0, stream>>>(
      qkv1, LX, qkv1, 0, LX, LX, pe, qsc, ksc, qh1, LX, kh1, LX);
  attn_kernel<0><<<NHEAD * (LX / 64), 512, 0, stream>>>(
      qh1, kh1, vh1, LX, vh1, LX, 0, 0, LX, LX, LX, LX, LX / 64, cat1);
  // split-K=5: K 7680 -> 5 x 1536, grid 510 blocks (~2 rounds of 256 CUs)
  gemm256<2><<<dim3(HID / 256, LX / 256, 5), 512, 0, stream>>>(
      cat1, w2b, LX, CATK / 5, CATK, b2, nullptr, nullptr, nullptr, 0,
      nullptr, mvec + 3072, out);

  // ---- block 2 (only 20 concept queries matter; k/v of image rows reused from block 1) ----
  ln_mod_kernel<<<NCON, 256, 0, stream>>>(con, mvec, xm2, nullptr, nullptr);
  gemm_bt<0><<<dim3(NQKV / 128, 1), 256, 0, stream>>>(
      xm2, w1b, NCON, HID, b1, qkv2, cat2, vh2s, 32, nullptr, nullptr, nullptr);
  qk_prep<<<(LC2 * NHEAD + 3) / 4, 256, 0, stream>>>(
      qkv2, NCON, qkv1, 236, LC2, NCON, cpe, qsc, ksc, qh2, 64, kh2, LC2);
  attn_kernel<1><<<NHEAD, 512, 0, stream>>>(
      qh2, kh2, vh2s, 32, vh1, LX, 236, NCON, NCON, LC2, 64, LC2, 1, cat2);
  gemm_bt<1><<<dim3(HID / 128, 1), 256, 0, stream>>>(
      cat2, w2b, NCON, CATK, b2, nullptr, nullptr, nullptr, 0, con, mvec + 3072,
      out + (size_t)LX * HID);
}